// Round 10
// baseline (119.675 us; speedup 1.0000x reference)
//
#include <hip/hip_runtime.h>
#include <hip/hip_bf16.h>

#define SEQ 4096
#define DIM 512
#define SCALE 0.044194173824159216f  // 1/sqrt(512)

#define SPLITS 4
#define BQ 64
#define KVBLK 64
#define KEYS_PER_SPLIT (SEQ / SPLITS)    // 1024
#define ITERS (KEYS_PER_SPLIT / KVBLK)   // 16
#define THR_DEFER 8.0f

typedef __attribute__((ext_vector_type(8))) short short8;
typedef __attribute__((ext_vector_type(4))) float f32x4;
typedef __attribute__((ext_vector_type(16))) float f32x16;

__device__ __forceinline__ short f2bf(float f) {
  union { float f; unsigned u; } c; c.f = f;
  unsigned u = c.u;
  return (short)((u + 0x7FFFu + ((u >> 16) & 1u)) >> 16);
}

__device__ __forceinline__ short8 pack8(float4 a, float4 b) {
  short8 r;
  r[0] = f2bf(a.x); r[1] = f2bf(a.y); r[2] = f2bf(a.z); r[3] = f2bf(a.w);
  r[4] = f2bf(b.x); r[5] = f2bf(b.y); r[6] = f2bf(b.z); r[7] = f2bf(b.w);
  return r;
}

__device__ __forceinline__ ushort4 pack4(float a, float b, float c, float d) {
  ushort4 r;
  r.x = (unsigned short)f2bf(a); r.y = (unsigned short)f2bf(b);
  r.z = (unsigned short)f2bf(c); r.w = (unsigned short)f2bf(d);
  return r;
}

// async global->LDS, 16B per lane, dest = uniform base + lane*16
__device__ __forceinline__ void gload16(const void* g, void* l) {
  __builtin_amdgcn_global_load_lds(
      (const __attribute__((address_space(1))) unsigned int*)g,
      (__attribute__((address_space(3))) unsigned int*)l, 16, 0, 0);
}

// ---------- prep: fp32 -> bf16 row-major (for K) ----------
__global__ void cvt_bf16(const float* __restrict__ in, ushort* __restrict__ ob, int n8) {
  int i = blockIdx.x * blockDim.x + threadIdx.x;
  if (i >= n8) return;
  const float4* p = (const float4*)(in + (size_t)i * 8);
  short8 v = pack8(p[0], p[1]);
  *(short8*)(ob + (size_t)i * 8) = v;
}

// ---------- prep: fp32 V (S x D) -> bf16 tiled V^T: vtp[d/32][s/8][32][8] ----------
// Matches 32x32x16 MFMA B-frag footprint: a wave's frag load = contiguous 512B x2.
__global__ void transpose_tile_bf16(const float* __restrict__ v, ushort* __restrict__ vtp) {
  __shared__ float t[64][65];
  const int bs = blockIdx.x % (SEQ / 64);
  const int bd = blockIdx.x / (SEQ / 64);
  const int s0t = bs * 64, d0t = bd * 64;
  const int tid = threadIdx.x;
#pragma unroll
  for (int k = 0; k < 16; ++k) {
    int idx = k * 256 + tid;
    int r = idx >> 6, c = idx & 63;          // r = s-local, c = d-local
    t[r][c] = v[(size_t)(s0t + r) * DIM + d0t + c];
  }
  __syncthreads();
#pragma unroll
  for (int k = 0; k < 16; ++k) {
    int dd = (tid >> 3) & 31, ss = tid & 7;
    int dl = (k & 1) * 32 + dd;
    int sl = (k >> 1) * 8 + ss;
    int d = d0t + dl, s = s0t + sl;
    size_t o = ((size_t)(d >> 5) * (SEQ / 8) + (s >> 3)) * 256 + (d & 31) * 8 + (s & 7);
    vtp[o] = (ushort)f2bf(t[sl][dl]);
  }
}

// ---------- fused attention: K dbuf + QK(t+1)||SM(t), V tiled global->reg ----------
// QK/SM role: rg=w&3 (16 q-rows), kh=w>>2 (32-key half). Swapped QK^T -> in-reg SM.
// PV role: wave w -> cols w*64..+64, ALL 64 q-rows, 32x32x16 MFMA, B=V from regs.
// Counted-vmcnt queue per iter: [K(t+1) 8 | V(t) 8 | K(t+2) 8]
//   pre-BAR-top: vmcnt(16)  (drain K(t+1) only)
//   pre-PV:      vmcnt(8)   (drain V(t); K(t+2) stays in flight)
__global__ __launch_bounds__(512, 1) void attn_split(
    const float* __restrict__ q, const ushort* __restrict__ kbf,
    const ushort* __restrict__ vtp, float* __restrict__ opart,
    float* __restrict__ ml) {
  __shared__ __align__(16) ushort kt[2][KVBLK * DIM];  // 2x64 KB, g16 ^= row&31
  __shared__ __align__(16) ushort p_lds[BQ * KVBLK];   // 8 KB, byte ^= (row&7)<<4
  __shared__ float mx_st[2][2][BQ];                    // [parity][kh][row]
  __shared__ float osc_st[BQ];
  __shared__ float l_st[2][BQ];
  __shared__ int   flag_st[4];

  const int tid  = threadIdx.x;
  const int lane = tid & 63;
  const int w    = tid >> 6;
  const int lr   = lane & 15;
  const int lg   = lane >> 4;
  const int l31  = lane & 31;
  const int hi   = lane >> 5;
  const int sp   = blockIdx.x & (SPLITS - 1);
  const int qb   = blockIdx.x >> 2;
  const int rg   = w & 3;
  const int kh   = w >> 2;
  const int qrow0 = qb * BQ;
  const int kbase = sp * KEYS_PER_SPLIT;

  // Q fragments (B-operand 16x16x32): col=qrow=lr, k=lg*8+j
  short8 qf[16];
  {
    const float* qp = q + (size_t)(qrow0 + rg * 16 + lr) * DIM + lg * 8;
#pragma unroll
    for (int c = 0; c < 16; ++c)
      qf[c] = pack8(*(const float4*)(qp + c * 32), *(const float4*)(qp + c * 32 + 4));
  }
  f32x16 oacc[4] = {};  // [rt*2+dt]: rows rt*32..+32, cols w*64+dt*32..+32
  float m_reg = -INFINITY, l_reg = 0.f;

  // K rows 1KB: LDS[r][g16] = K[kb+r][(g16 ^ (r&31))*8..]; 8 gloads/wave
  auto stageK = [&](int kb, int buf) {
#pragma unroll
    for (int i = 0; i < 8; ++i) {
      int r = w * 8 + i;
      const ushort* src = kbf + (size_t)(kb + r) * DIM + ((lane ^ (r & 31)) * 8);
      gload16(src, &kt[buf][r * DIM]);
    }
  };

  // swapped QK^T (16x16x32): two 16-key chains; S^T[key][qrow=lr]
  auto qk = [&](int buf, f32x4& s0, f32x4& s1) {
    const int kr0 = kh * 32 + lr;
    const int kr1 = kr0 + 16;
    const char* kb0 = (const char*)&kt[buf][kr0 * DIM];
    const char* kb1 = (const char*)&kt[buf][kr1 * DIM];
    const int sw0 = kr0 & 31, sw1 = kr1 & 31;
    __builtin_amdgcn_s_setprio(1);
#pragma unroll
    for (int c = 0; c < 16; ++c) {
      short8 k0 = *(const short8*)(kb0 + (((c * 4 + lg) ^ sw0) << 4));
      short8 k1 = *(const short8*)(kb1 + (((c * 4 + lg) ^ sw1) << 4));
      s0 = __builtin_amdgcn_mfma_f32_16x16x32_bf16(k0, qf[c], s0, 0, 0, 0);
      s1 = __builtin_amdgcn_mfma_f32_16x16x32_bf16(k1, qf[c], s1, 0, 0, 0);
    }
    __builtin_amdgcn_s_setprio(0);
  };

  // ---- prologue: K(0)->b0, K(1)->b1; QK(0) ----
  stageK(kbase, 0);
  stageK(kbase + KVBLK, 1);
  asm volatile("s_waitcnt vmcnt(8)" ::: "memory");  // K(0) landed, K(1) in flight
  __builtin_amdgcn_s_barrier();

  float scA[8];
  {
    f32x4 s0 = {}, s1 = {};
    qk(0, s0, s1);
#pragma unroll
    for (int r = 0; r < 4; ++r) { scA[r] = s0[r] * SCALE; scA[4 + r] = s1[r] * SCALE; }
    float tm = fmaxf(fmaxf(fmaxf(scA[0], scA[1]), fmaxf(scA[2], scA[3])),
                     fmaxf(fmaxf(scA[4], scA[5]), fmaxf(scA[6], scA[7])));
    tm = fmaxf(tm, __shfl_xor(tm, 16));
    tm = fmaxf(tm, __shfl_xor(tm, 32));
    if (lane < 16) mx_st[0][kh][rg * 16 + lane] = tm;
  }
  asm volatile("s_waitcnt lgkmcnt(0)" ::: "memory");  // mx(0) flushed (published at BAR-top t=0)

#pragma unroll 1
  for (int t = 0; t < ITERS; ++t) {
    const int cur = t & 1, nxt = cur ^ 1;
    const int kb = kbase + t * KVBLK;
    const bool hn = (t + 1 < ITERS);
    const bool k2 = (t + 2 < ITERS);

    // ---- V(t) -> registers (tiled layout, coalesced, L2-served) ----
    short8 vreg[8];
#pragma unroll
    for (int dt = 0; dt < 2; ++dt)
#pragma unroll
      for (int kc = 0; kc < 4; ++kc) {
        int d0 = w * 2 + dt;
        int s0i = (kb >> 3) + kc * 2 + hi;
        vreg[dt * 4 + kc] =
            *(const short8*)(vtp + ((size_t)(d0 * (SEQ / 8) + s0i) * 256 + l31 * 8));
      }

    // ---- stage K(t+2) into kt[cur] (all QK(t) readers drained at BAR-mid(t-1)) ----
    if (k2) stageK(kbase + (t + 2) * KVBLK, cur);

    // drain own K(t+1) only; V(t) + K(t+2) stay in flight
    if (k2)      asm volatile("s_waitcnt vmcnt(16)" ::: "memory");
    else         asm volatile("s_waitcnt vmcnt(8)" ::: "memory");
    __builtin_amdgcn_s_barrier();  // BAR-top: kt[nxt]/mx(t) visible, p_lds free

    // ---- QK(t+1) (MFMA, kt[nxt]) — overlaps SM(t) VALU ----
    f32x4 n0 = {}, n1 = {};
    if (hn) qk(nxt, n0, n1);

    // ---- SM(t): common m across kh pair, defer-max, P -> p_lds ----
    {
      const int row = rg * 16 + lr;
      float tmax64 = fmaxf(mx_st[cur][0][row], mx_st[cur][1][row]);
      bool resc = tmax64 > m_reg + THR_DEFER;
      float mnew = resc ? tmax64 : m_reg;
      float osc = __expf(m_reg - mnew);  // 1.0 deferred; 0 on first tile
      unsigned long long bl = __ballot(resc);
      if (kh == 0 && lane == 0) flag_st[rg] = (bl != 0ull) ? 1 : 0;
      if (kh == 0 && lane < 16) osc_st[row] = osc;
      m_reg = mnew;
      l_reg *= osc;
      float p0[8];
#pragma unroll
      for (int r = 0; r < 8; ++r) p0[r] = __expf(scA[r] - m_reg);
      float ps = ((p0[0] + p0[1]) + (p0[2] + p0[3])) +
                 ((p0[4] + p0[5]) + (p0[6] + p0[7]));
      ps += __shfl_xor(ps, 16);
      ps += __shfl_xor(ps, 32);
      l_reg += ps;
      char* pb = (char*)p_lds + row * 128;
      const int sw = (row & 7) << 4;
      const int off = kh * 64 + lg * 8;
      *(ushort4*)(pb + (off ^ sw))        = pack4(p0[0], p0[1], p0[2], p0[3]);
      *(ushort4*)(pb + ((off + 32) ^ sw)) = pack4(p0[4], p0[5], p0[6], p0[7]);
    }

    // ---- finish tile t+1 pre-softmax (scale + tile max -> mx[nxt]) ----
    if (hn) {
#pragma unroll
      for (int r = 0; r < 4; ++r) { scA[r] = n0[r] * SCALE; scA[4 + r] = n1[r] * SCALE; }
      float tm = fmaxf(fmaxf(fmaxf(scA[0], scA[1]), fmaxf(scA[2], scA[3])),
                       fmaxf(fmaxf(scA[4], scA[5]), fmaxf(scA[6], scA[7])));
      tm = fmaxf(tm, __shfl_xor(tm, 16));
      tm = fmaxf(tm, __shfl_xor(tm, 32));
      if (lane < 16) mx_st[nxt][kh][rg * 16 + lane] = tm;
    }

    asm volatile("s_waitcnt lgkmcnt(0)" ::: "memory");  // p/mx/osc/flag flushed
    __builtin_amdgcn_s_barrier();                       // BAR-mid

    // ---- PV(t) (32x32x16): all 64 rows, cols w*64..+64 ----
    {
#pragma unroll
      for (int rt = 0; rt < 2; ++rt) {
        if (flag_st[rt * 2] | flag_st[rt * 2 + 1]) {
          float ov[16];
#pragma unroll
          for (int r = 0; r < 16; ++r)
            ov[r] = osc_st[rt * 32 + (r & 3) + 8 * (r >> 2) + 4 * hi];
#pragma unroll
          for (int dt = 0; dt < 2; ++dt)
#pragma unroll
            for (int r = 0; r < 16; ++r) oacc[rt * 2 + dt][r] *= ov[r];
        }
      }
      // drain V(t); K(t+2) remains in flight across the iteration boundary
      if (k2) asm volatile("s_waitcnt vmcnt(8)" ::: "memory");
      else    asm volatile("s_waitcnt vmcnt(0)" ::: "memory");
      __builtin_amdgcn_s_setprio(1);
#pragma unroll
      for (int kc = 0; kc < 4; ++kc)
#pragma unroll
        for (int rt = 0; rt < 2; ++rt) {
          const int arow = rt * 32 + l31;
          short8 pa = *(const short8*)((const char*)p_lds + arow * 128 +
                                       ((kc * 32 + hi * 16) ^ ((arow & 7) << 4)));
#pragma unroll
          for (int dt = 0; dt < 2; ++dt)
            oacc[rt * 2 + dt] = __builtin_amdgcn_mfma_f32_32x32x16_bf16(
                pa, vreg[dt * 4 + kc], oacc[rt * 2 + dt], 0, 0, 0);
        }
      __builtin_amdgcn_s_setprio(0);
    }
  }

  // ---- epilogue: merge l across kh, write opart + ml ----
  if (lane < 16) {
    l_st[kh][rg * 16 + lane] = l_reg;
    if (kh == 0) mx_st[0][0][rg * 16 + lane] = m_reg;
  }
  __syncthreads();
  {
    float* op = opart + ((size_t)sp * SEQ + qrow0) * DIM + w * 64;
#pragma unroll
    for (int rt = 0; rt < 2; ++rt)
#pragma unroll
      for (int dt = 0; dt < 2; ++dt)
#pragma unroll
        for (int r = 0; r < 16; ++r) {
          int crow = rt * 32 + (r & 3) + 8 * (r >> 2) + 4 * hi;
          op[(size_t)crow * DIM + dt * 32 + l31] = oacc[rt * 2 + dt][r];
        }
  }
  if (tid < BQ) {
    size_t base = ((size_t)sp * SEQ + qrow0 + tid) * 2;
    ml[base]     = mx_st[0][0][tid];
    ml[base + 1] = l_st[0][tid] + l_st[1][tid];
  }
}

// ---------- combine split partials ----------
__global__ void combine(const float* __restrict__ opart, const float* __restrict__ ml,
                        float* __restrict__ out) {
  int gid = blockIdx.x * 256 + threadIdx.x;
  int row = gid >> 7;
  int dv  = (gid & 127) * 4;
  float m[SPLITS], l[SPLITS], wgt[SPLITS];
  float M = -INFINITY;
#pragma unroll
  for (int i = 0; i < SPLITS; ++i) {
    m[i] = ml[((size_t)i * SEQ + row) * 2];
    l[i] = ml[((size_t)i * SEQ + row) * 2 + 1];
    M = fmaxf(M, m[i]);
  }
  float L = 0.f;
#pragma unroll
  for (int i = 0; i < SPLITS; ++i) { wgt[i] = __expf(m[i] - M); L += l[i] * wgt[i]; }
  float inv = 1.f / L;
  float4 acc = {0.f, 0.f, 0.f, 0.f};
#pragma unroll
  for (int i = 0; i < SPLITS; ++i) {
    float4 o = *(const float4*)(opart + ((size_t)i * SEQ + row) * DIM + dv);
    acc.x += o.x * wgt[i]; acc.y += o.y * wgt[i];
    acc.z += o.z * wgt[i]; acc.w += o.w * wgt[i];
  }
  acc.x *= inv; acc.y *= inv; acc.z *= inv; acc.w *= inv;
  *(float4*)(out + (size_t)row * DIM + dv) = acc;
}

// ---------- fallback if ws too small ----------
__global__ __launch_bounds__(512) void attn_fused_fb(
    const float* __restrict__ q, const float* __restrict__ k,
    const float* __restrict__ v, float* __restrict__ out) {
  __shared__ float s_lds[16][128];
  __shared__ __align__(16) unsigned short p_lds[16 * 128];
  __shared__ float m_st[16], l_st[16], osc_st[16];
  const int tid = threadIdx.x, lane = tid & 63, w = tid >> 6;
  const int lr = lane & 15, lg = lane >> 4, qb = blockIdx.x * 16;
  if (tid < 16) { m_st[tid] = -INFINITY; l_st[tid] = 0.f; }
  short8 qf[16];
  {
    const float* qp = q + (size_t)(qb + lr) * DIM + lg * 8;
#pragma unroll
    for (int c = 0; c < 16; ++c)
      qf[c] = pack8(*(const float4*)(qp + c * 32), *(const float4*)(qp + c * 32 + 4));
  }
  f32x4 oacc[4] = {};
  __syncthreads();
  for (int it = 0; it < SEQ / 128; ++it) {
    const int kb = it * 128;
    {
      const float* kp = k + (size_t)(kb + w * 16 + lr) * DIM + lg * 8;
      f32x4 sacc = {};
#pragma unroll
      for (int c = 0; c < 16; ++c) {
        short8 kf = pack8(*(const float4*)(kp + c * 32), *(const float4*)(kp + c * 32 + 4));
        sacc = __builtin_amdgcn_mfma_f32_16x16x32_bf16(qf[c], kf, sacc, 0, 0, 0);
      }
#pragma unroll
      for (int r = 0; r < 4; ++r) s_lds[lg * 4 + r][w * 16 + lr] = sacc[r] * SCALE;
    }
    __syncthreads();
    {
      const int srow = tid >> 5, sj = tid & 31;
      float4 sv = *(const float4*)&s_lds[srow][sj * 4];
      float tmax = fmaxf(fmaxf(sv.x, sv.y), fmaxf(sv.z, sv.w));
#pragma unroll
      for (int m = 16; m >= 1; m >>= 1) tmax = fmaxf(tmax, __shfl_xor(tmax, m));
      float mold = m_st[srow], mnew = fmaxf(mold, tmax);
      float p0 = __expf(sv.x - mnew), p1 = __expf(sv.y - mnew);
      float p2 = __expf(sv.z - mnew), p3 = __expf(sv.w - mnew);
      float psum = (p0 + p1) + (p2 + p3);
#pragma unroll
      for (int m = 16; m >= 1; m >>= 1) psum += __shfl_xor(psum, m);
      if (sj == 0) {
        float sc = __expf(mold - mnew);
        l_st[srow] = l_st[srow] * sc + psum; m_st[srow] = mnew; osc_st[srow] = sc;
      }
      ushort4 pb;
      pb.x = (unsigned short)f2bf(p0); pb.y = (unsigned short)f2bf(p1);
      pb.z = (unsigned short)f2bf(p2); pb.w = (unsigned short)f2bf(p3);
      int lin = srow * 256 + sj * 8;
      *(ushort4*)((char*)p_lds + (lin ^ ((srow & 7) << 4))) = pb;
    }
    __syncthreads();
    {
      float osc[4];
#pragma unroll
      for (int r = 0; r < 4; ++r) osc[r] = osc_st[lg * 4 + r];
#pragma unroll
      for (int ct = 0; ct < 4; ++ct)
#pragma unroll
        for (int r = 0; r < 4; ++r) oacc[ct][r] *= osc[r];
#pragma unroll
      for (int kc = 0; kc < 4; ++kc) {
        int lin = lr * 256 + (kc * 32 + 8 * lg) * 2;
        short8 pf = *(const short8*)((const char*)p_lds + (lin ^ ((lr & 7) << 4)));
        const float* vp0 = v + (size_t)(kb + kc * 32 + 8 * lg) * DIM + w * 64 + lr;
#pragma unroll
        for (int ct = 0; ct < 4; ++ct) {
          const float* vp = vp0 + ct * 16;
          short8 vf;
#pragma unroll
          for (int jj = 0; jj < 8; ++jj) vf[jj] = f2bf(vp[(size_t)jj * DIM]);
          oacc[ct] = __builtin_amdgcn_mfma_f32_16x16x32_bf16(pf, vf, oacc[ct], 0, 0, 0);
        }
      }
    }
    __syncthreads();
  }
  {
    float linv[4];
#pragma unroll
    for (int r = 0; r < 4; ++r) linv[r] = 1.f / l_st[lg * 4 + r];
#pragma unroll
    for (int ct = 0; ct < 4; ++ct)
#pragma unroll
      for (int r = 0; r < 4; ++r)
        out[(size_t)(qb + lg * 4 + r) * DIM + w * 64 + ct * 16 + lr] =
            oacc[ct][r] * linv[r];
  }
}

extern "C" void kernel_launch(void* const* d_in, const int* in_sizes, int n_in,
                              void* d_out, int out_size, void* d_ws, size_t ws_size,
                              hipStream_t stream) {
  (void)in_sizes; (void)n_in; (void)out_size;
  const float* q = (const float*)d_in[0];
  const float* k = (const float*)d_in[1];
  const float* v = (const float*)d_in[2];
  float* out = (float*)d_out;

  const size_t kbf_elems = (size_t)SEQ * DIM;
  const size_t vt_elems  = (size_t)DIM * SEQ;
  const size_t op_elems  = (size_t)SPLITS * SEQ * DIM;
  const size_t ml_elems  = (size_t)SPLITS * SEQ * 2;
  const size_t need = kbf_elems * 2 + vt_elems * 2 + op_elems * 4 + ml_elems * 4;

  if (ws_size >= need) {
    ushort* kbf  = (ushort*)d_ws;
    ushort* vtp  = kbf + kbf_elems;
    float* opart = (float*)(vtp + vt_elems);
    float* ml    = opart + op_elems;

    cvt_bf16<<<(SEQ * DIM / 8 + 255) / 256, 256, 0, stream>>>(k, kbf, SEQ * DIM / 8);
    transpose_tile_bf16<<<(SEQ / 64) * (DIM / 64), 256, 0, stream>>>(v, vtp);
    attn_split<<<(SEQ / BQ) * SPLITS, 512, 0, stream>>>(q, kbf, vtp, opart, ml);
    combine<<<(SEQ * DIM / 4) / 256, 256, 0, stream>>>(opart, ml, out);
  } else {
    attn_fused_fb<<<SEQ / 16, 512, 0, stream>>>(q, k, v, out);
  }
}

// Round 11
// 112.936 us; speedup vs baseline: 1.0597x; 1.0597x over previous
//
#include <hip/hip_runtime.h>
#include <hip/hip_bf16.h>

#define SEQ 4096
#define DIM 512
#define SCALE 0.044194173824159216f  // 1/sqrt(512)

#define SPLITS 4
#define BQ 64
#define KVBLK 64
#define KEYS_PER_SPLIT (SEQ / SPLITS)    // 1024
#define ITERS (KEYS_PER_SPLIT / KVBLK)   // 16
#define THR_DEFER 8.0f

typedef __attribute__((ext_vector_type(8))) short short8;
typedef __attribute__((ext_vector_type(4))) float f32x4;
typedef __attribute__((ext_vector_type(16))) float f32x16;

__device__ __forceinline__ short f2bf(float f) {
  union { float f; unsigned u; } c; c.f = f;
  unsigned u = c.u;
  return (short)((u + 0x7FFFu + ((u >> 16) & 1u)) >> 16);
}

__device__ __forceinline__ short8 pack8(float4 a, float4 b) {
  short8 r;
  r[0] = f2bf(a.x); r[1] = f2bf(a.y); r[2] = f2bf(a.z); r[3] = f2bf(a.w);
  r[4] = f2bf(b.x); r[5] = f2bf(b.y); r[6] = f2bf(b.z); r[7] = f2bf(b.w);
  return r;
}

__device__ __forceinline__ ushort4 pack4(float a, float b, float c, float d) {
  ushort4 r;
  r.x = (unsigned short)f2bf(a); r.y = (unsigned short)f2bf(b);
  r.z = (unsigned short)f2bf(c); r.w = (unsigned short)f2bf(d);
  return r;
}

// async global->LDS, 16B per lane, dest = uniform base + lane*16
__device__ __forceinline__ void gload16(const void* g, void* l) {
  __builtin_amdgcn_global_load_lds(
      (const __attribute__((address_space(1))) unsigned int*)g,
      (__attribute__((address_space(3))) unsigned int*)l, 16, 0, 0);
}

// ---------- prep: fp32 -> bf16 row-major (for K) ----------
__global__ void cvt_bf16(const float* __restrict__ in, ushort* __restrict__ ob, int n8) {
  int i = blockIdx.x * blockDim.x + threadIdx.x;
  if (i >= n8) return;
  const float4* p = (const float4*)(in + (size_t)i * 8);
  short8 v = pack8(p[0], p[1]);
  *(short8*)(ob + (size_t)i * 8) = v;
}

// ---------- prep: fp32 V (S x D) -> bf16 tiled V^T: vtp[d/32][s/8][32][8] ----------
// Matches 32x32x16 MFMA B-frag footprint: a wave's frag load = contiguous 512B x2.
__global__ void transpose_tile_bf16(const float* __restrict__ v, ushort* __restrict__ vtp) {
  __shared__ float t[64][65];
  const int bs = blockIdx.x % (SEQ / 64);
  const int bd = blockIdx.x / (SEQ / 64);
  const int s0t = bs * 64, d0t = bd * 64;
  const int tid = threadIdx.x;
#pragma unroll
  for (int k = 0; k < 16; ++k) {
    int idx = k * 256 + tid;
    int r = idx >> 6, c = idx & 63;          // r = s-local, c = d-local
    t[r][c] = v[(size_t)(s0t + r) * DIM + d0t + c];
  }
  __syncthreads();
#pragma unroll
  for (int k = 0; k < 16; ++k) {
    int dd = (tid >> 3) & 31, ss = tid & 7;
    int dl = (k & 1) * 32 + dd;
    int sl = (k >> 1) * 8 + ss;
    int d = d0t + dl, s = s0t + sl;
    size_t o = ((size_t)(d >> 5) * (SEQ / 8) + (s >> 3)) * 256 + (d & 31) * 8 + (s & 7);
    vtp[o] = (ushort)f2bf(t[sl][dl]);
  }
}

// ---------- fused attention: round-6 schedule, V tiled global->regs ----------
// QK/SM role: rg=w&3 (16 q-rows), kh=w>>2 (32-key half). Swapped QK^T -> in-reg SM.
// PV role: wave w -> ALL 64 q-rows, cols w*64..+64, 32x32x16 MFMA, B=V from regs.
// Per iter (3 barriers):
//   QK(t) -> lgkm -> BAR-B -> [vreg V(t) issue | stageK(t+1) issue | SM(t)]
//   -> lgkm -> BAR-C -> [rescale, vmcnt(8)=V ready, PV(t)] -> vmcnt(0) -> BAR-A
__global__ __launch_bounds__(512) void attn_split(
    const float* __restrict__ q, const ushort* __restrict__ kbf,
    const ushort* __restrict__ vtp, float* __restrict__ opart,
    float* __restrict__ ml) {
  __shared__ __align__(16) ushort kt[KVBLK * DIM];    // 64 KB, g16 ^= row&31
  __shared__ __align__(16) ushort p_lds[BQ * KVBLK];  // 8 KB, byte ^= (row&7)<<4
  __shared__ float mx_st[2][BQ];                      // [kh][row] tile max
  __shared__ float osc_st[BQ];
  __shared__ float l_st[2][BQ];
  __shared__ int   flag_st[4];

  const int tid  = threadIdx.x;
  const int lane = tid & 63;
  const int w    = tid >> 6;
  const int lr   = lane & 15;
  const int lg   = lane >> 4;
  const int l31  = lane & 31;
  const int hi   = lane >> 5;
  const int sp   = blockIdx.x & (SPLITS - 1);
  const int qb   = blockIdx.x >> 2;
  const int rg   = w & 3;
  const int kh   = w >> 2;
  const int qrow0 = qb * BQ;
  const int kbase = sp * KEYS_PER_SPLIT;

  // Q fragments (B-operand 16x16x32): col=qrow=lr, k=lg*8+j
  short8 qf[16];
  {
    const float* qp = q + (size_t)(qrow0 + rg * 16 + lr) * DIM + lg * 8;
#pragma unroll
    for (int c = 0; c < 16; ++c)
      qf[c] = pack8(*(const float4*)(qp + c * 32), *(const float4*)(qp + c * 32 + 4));
  }
  f32x16 oacc[4] = {};  // [rt*2+dt]: rows rt*32..+32, cols w*64+dt*32..+32
  float m_reg = -INFINITY, l_reg = 0.f;

  // K rows 1KB: LDS[r][g16] = K[kb+r][(g16 ^ (r&31))*8..]; 8 gloads/wave
  auto stageK = [&](int kb) {
#pragma unroll
    for (int i = 0; i < 8; ++i) {
      int r = w * 8 + i;
      const ushort* src = kbf + (size_t)(kb + r) * DIM + ((lane ^ (r & 31)) * 8);
      gload16(src, &kt[r * DIM]);
    }
  };

  // ---- prologue: K(0) staged, drained ----
  stageK(kbase);
  asm volatile("s_waitcnt vmcnt(0)" ::: "memory");
  __builtin_amdgcn_s_barrier();

#pragma unroll 1
  for (int t = 0; t < ITERS; ++t) {
    const int kb = kbase + t * KVBLK;
    const bool hn = (t + 1 < ITERS);

    // ---- QK(t): swapped (16x16x32), S^T[key][qrow=lr], 32 keys/wave ----
    float scA[8];
    {
      const int kr0 = kh * 32 + lr;
      const int kr1 = kr0 + 16;
      const char* kb0 = (const char*)&kt[kr0 * DIM];
      const char* kb1 = (const char*)&kt[kr1 * DIM];
      const int sw0 = kr0 & 31, sw1 = kr1 & 31;
      f32x4 s0 = {}, s1 = {};
      __builtin_amdgcn_s_setprio(1);
#pragma unroll
      for (int c = 0; c < 16; ++c) {
        short8 k0 = *(const short8*)(kb0 + (((c * 4 + lg) ^ sw0) << 4));
        short8 k1 = *(const short8*)(kb1 + (((c * 4 + lg) ^ sw1) << 4));
        s0 = __builtin_amdgcn_mfma_f32_16x16x32_bf16(k0, qf[c], s0, 0, 0, 0);
        s1 = __builtin_amdgcn_mfma_f32_16x16x32_bf16(k1, qf[c], s1, 0, 0, 0);
      }
      __builtin_amdgcn_s_setprio(0);
#pragma unroll
      for (int r = 0; r < 4; ++r) { scA[r] = s0[r] * SCALE; scA[4 + r] = s1[r] * SCALE; }
      float tm = fmaxf(fmaxf(fmaxf(scA[0], scA[1]), fmaxf(scA[2], scA[3])),
                       fmaxf(fmaxf(scA[4], scA[5]), fmaxf(scA[6], scA[7])));
      tm = fmaxf(tm, __shfl_xor(tm, 16));
      tm = fmaxf(tm, __shfl_xor(tm, 32));
      if (lane < 16) mx_st[kh][rg * 16 + lane] = tm;
    }
    asm volatile("s_waitcnt lgkmcnt(0)" ::: "memory");
    __builtin_amdgcn_s_barrier();  // BAR-B: kt consumed by all, mx visible

    // ---- V(t) -> registers FIRST (queue: [V 8 | K 8] so vmcnt(8) drains V) ----
    short8 vreg[8];
#pragma unroll
    for (int dt = 0; dt < 2; ++dt)
#pragma unroll
      for (int kc = 0; kc < 4; ++kc) {
        int d0 = w * 2 + dt;
        int s0i = (kb >> 3) + kc * 2 + hi;
        vreg[dt * 4 + kc] =
            *(const short8*)(vtp + ((size_t)(d0 * (SEQ / 8) + s0i) * 256 + l31 * 8));
      }

    // ---- stage K(t+1) (kt free: all QK(t) reads drained at BAR-B) ----
    if (hn) stageK(kbase + (t + 1) * KVBLK);

    // ---- SM(t): common m across kh pair, defer-max, P -> p_lds ----
    {
      const int row = rg * 16 + lr;
      float tmax64 = fmaxf(mx_st[0][row], mx_st[1][row]);
      bool resc = tmax64 > m_reg + THR_DEFER;
      float mnew = resc ? tmax64 : m_reg;
      float osc = __expf(m_reg - mnew);  // 1.0 deferred; 0 on first tile
      unsigned long long bl = __ballot(resc);
      if (kh == 0 && lane == 0) flag_st[rg] = (bl != 0ull) ? 1 : 0;
      if (kh == 0 && lane < 16) osc_st[row] = osc;
      m_reg = mnew;
      l_reg *= osc;
      float p0[8];
#pragma unroll
      for (int r = 0; r < 8; ++r) p0[r] = __expf(scA[r] - m_reg);
      float ps = ((p0[0] + p0[1]) + (p0[2] + p0[3])) +
                 ((p0[4] + p0[5]) + (p0[6] + p0[7]));
      ps += __shfl_xor(ps, 16);
      ps += __shfl_xor(ps, 32);
      l_reg += ps;
      char* pb = (char*)p_lds + row * 128;
      const int sw = (row & 7) << 4;
      const int off = kh * 64 + lg * 8;
      *(ushort4*)(pb + (off ^ sw))        = pack4(p0[0], p0[1], p0[2], p0[3]);
      *(ushort4*)(pb + ((off + 32) ^ sw)) = pack4(p0[4], p0[5], p0[6], p0[7]);
    }
    asm volatile("s_waitcnt lgkmcnt(0)" ::: "memory");  // p/osc/flag flushed
    __builtin_amdgcn_s_barrier();                       // BAR-C

    // ---- PV(t) (32x32x16): all 64 rows, cols w*64..+64, B=V regs ----
    {
#pragma unroll
      for (int rt = 0; rt < 2; ++rt) {
        if (flag_st[rt * 2] | flag_st[rt * 2 + 1]) {
          float ov[16];
#pragma unroll
          for (int r = 0; r < 16; ++r)
            ov[r] = osc_st[rt * 32 + (r & 3) + 8 * (r >> 2) + 4 * hi];
#pragma unroll
          for (int dt = 0; dt < 2; ++dt)
#pragma unroll
            for (int r = 0; r < 16; ++r) oacc[rt * 2 + dt][r] *= ov[r];
        }
      }
      // drain V(t) only; K(t+1) stays in flight through PV
      if (hn) asm volatile("s_waitcnt vmcnt(8)" ::: "memory");
      else    asm volatile("s_waitcnt vmcnt(0)" ::: "memory");
      __builtin_amdgcn_s_setprio(1);
#pragma unroll
      for (int kc = 0; kc < 4; ++kc)
#pragma unroll
        for (int rt = 0; rt < 2; ++rt) {
          const int arow = rt * 32 + l31;
          short8 pa = *(const short8*)((const char*)p_lds + arow * 128 +
                                       ((kc * 32 + hi * 16) ^ ((arow & 7) << 4)));
#pragma unroll
          for (int dt = 0; dt < 2; ++dt)
            oacc[rt * 2 + dt] = __builtin_amdgcn_mfma_f32_32x32x16_bf16(
                pa, vreg[dt * 4 + kc], oacc[rt * 2 + dt], 0, 0, 0);
        }
      __builtin_amdgcn_s_setprio(0);
    }

    // K(t+1) landed (had all of PV); p_lds reads drained by MFMA deps
    asm volatile("s_waitcnt vmcnt(0) lgkmcnt(0)" ::: "memory");
    __builtin_amdgcn_s_barrier();  // BAR-A: kt(t+1) ready, p_lds free
  }

  // ---- epilogue: merge l across kh, write opart + ml ----
  if (lane < 16) {
    l_st[kh][rg * 16 + lane] = l_reg;
    if (kh == 0) mx_st[0][rg * 16 + lane] = m_reg;
  }
  __syncthreads();
  {
    float* op = opart + ((size_t)sp * SEQ + qrow0) * DIM + w * 64;
#pragma unroll
    for (int rt = 0; rt < 2; ++rt)
#pragma unroll
      for (int dt = 0; dt < 2; ++dt)
#pragma unroll
        for (int r = 0; r < 16; ++r) {
          int crow = rt * 32 + (r & 3) + 8 * (r >> 2) + 4 * hi;
          op[(size_t)crow * DIM + dt * 32 + l31] = oacc[rt * 2 + dt][r];
        }
  }
  if (tid < BQ) {
    size_t base = ((size_t)sp * SEQ + qrow0 + tid) * 2;
    ml[base]     = mx_st[0][tid];
    ml[base + 1] = l_st[0][tid] + l_st[1][tid];
  }
}

// ---------- combine split partials ----------
__global__ void combine(const float* __restrict__ opart, const float* __restrict__ ml,
                        float* __restrict__ out) {
  int gid = blockIdx.x * 256 + threadIdx.x;
  int row = gid >> 7;
  int dv  = (gid & 127) * 4;
  float m[SPLITS], l[SPLITS], wgt[SPLITS];
  float M = -INFINITY;
#pragma unroll
  for (int i = 0; i < SPLITS; ++i) {
    m[i] = ml[((size_t)i * SEQ + row) * 2];
    l[i] = ml[((size_t)i * SEQ + row) * 2 + 1];
    M = fmaxf(M, m[i]);
  }
  float L = 0.f;
#pragma unroll
  for (int i = 0; i < SPLITS; ++i) { wgt[i] = __expf(m[i] - M); L += l[i] * wgt[i]; }
  float inv = 1.f / L;
  float4 acc = {0.f, 0.f, 0.f, 0.f};
#pragma unroll
  for (int i = 0; i < SPLITS; ++i) {
    float4 o = *(const float4*)(opart + ((size_t)i * SEQ + row) * DIM + dv);
    acc.x += o.x * wgt[i]; acc.y += o.y * wgt[i];
    acc.z += o.z * wgt[i]; acc.w += o.w * wgt[i];
  }
  acc.x *= inv; acc.y *= inv; acc.z *= inv; acc.w *= inv;
  *(float4*)(out + (size_t)row * DIM + dv) = acc;
}

// ---------- fallback if ws too small ----------
__global__ __launch_bounds__(512) void attn_fused_fb(
    const float* __restrict__ q, const float* __restrict__ k,
    const float* __restrict__ v, float* __restrict__ out) {
  __shared__ float s_lds[16][128];
  __shared__ __align__(16) unsigned short p_lds[16 * 128];
  __shared__ float m_st[16], l_st[16], osc_st[16];
  const int tid = threadIdx.x, lane = tid & 63, w = tid >> 6;
  const int lr = lane & 15, lg = lane >> 4, qb = blockIdx.x * 16;
  if (tid < 16) { m_st[tid] = -INFINITY; l_st[tid] = 0.f; }
  short8 qf[16];
  {
    const float* qp = q + (size_t)(qb + lr) * DIM + lg * 8;
#pragma unroll
    for (int c = 0; c < 16; ++c)
      qf[c] = pack8(*(const float4*)(qp + c * 32), *(const float4*)(qp + c * 32 + 4));
  }
  f32x4 oacc[4] = {};
  __syncthreads();
  for (int it = 0; it < SEQ / 128; ++it) {
    const int kb = it * 128;
    {
      const float* kp = k + (size_t)(kb + w * 16 + lr) * DIM + lg * 8;
      f32x4 sacc = {};
#pragma unroll
      for (int c = 0; c < 16; ++c) {
        short8 kf = pack8(*(const float4*)(kp + c * 32), *(const float4*)(kp + c * 32 + 4));
        sacc = __builtin_amdgcn_mfma_f32_16x16x32_bf16(qf[c], kf, sacc, 0, 0, 0);
      }
#pragma unroll
      for (int r = 0; r < 4; ++r) s_lds[lg * 4 + r][w * 16 + lr] = sacc[r] * SCALE;
    }
    __syncthreads();
    {
      const int srow = tid >> 5, sj = tid & 31;
      float4 sv = *(const float4*)&s_lds[srow][sj * 4];
      float tmax = fmaxf(fmaxf(sv.x, sv.y), fmaxf(sv.z, sv.w));
#pragma unroll
      for (int m = 16; m >= 1; m >>= 1) tmax = fmaxf(tmax, __shfl_xor(tmax, m));
      float mold = m_st[srow], mnew = fmaxf(mold, tmax);
      float p0 = __expf(sv.x - mnew), p1 = __expf(sv.y - mnew);
      float p2 = __expf(sv.z - mnew), p3 = __expf(sv.w - mnew);
      float psum = (p0 + p1) + (p2 + p3);
#pragma unroll
      for (int m = 16; m >= 1; m >>= 1) psum += __shfl_xor(psum, m);
      if (sj == 0) {
        float sc = __expf(mold - mnew);
        l_st[srow] = l_st[srow] * sc + psum; m_st[srow] = mnew; osc_st[srow] = sc;
      }
      ushort4 pb;
      pb.x = (unsigned short)f2bf(p0); pb.y = (unsigned short)f2bf(p1);
      pb.z = (unsigned short)f2bf(p2); pb.w = (unsigned short)f2bf(p3);
      int lin = srow * 256 + sj * 8;
      *(ushort4*)((char*)p_lds + (lin ^ ((srow & 7) << 4))) = pb;
    }
    __syncthreads();
    {
      float osc[4];
#pragma unroll
      for (int r = 0; r < 4; ++r) osc[r] = osc_st[lg * 4 + r];
#pragma unroll
      for (int ct = 0; ct < 4; ++ct)
#pragma unroll
        for (int r = 0; r < 4; ++r) oacc[ct][r] *= osc[r];
#pragma unroll
      for (int kc = 0; kc < 4; ++kc) {
        int lin = lr * 256 + (kc * 32 + 8 * lg) * 2;
        short8 pf = *(const short8*)((const char*)p_lds + (lin ^ ((lr & 7) << 4)));
        const float* vp0 = v + (size_t)(kb + kc * 32 + 8 * lg) * DIM + w * 64 + lr;
#pragma unroll
        for (int ct = 0; ct < 4; ++ct) {
          const float* vp = vp0 + ct * 16;
          short8 vf;
#pragma unroll
          for (int jj = 0; jj < 8; ++jj) vf[jj] = f2bf(vp[(size_t)jj * DIM]);
          oacc[ct] = __builtin_amdgcn_mfma_f32_16x16x32_bf16(pf, vf, oacc[ct], 0, 0, 0);
        }
      }
    }
    __syncthreads();
  }
  {
    float linv[4];
#pragma unroll
    for (int r = 0; r < 4; ++r) linv[r] = 1.f / l_st[lg * 4 + r];
#pragma unroll
    for (int ct = 0; ct < 4; ++ct)
#pragma unroll
      for (int r = 0; r < 4; ++r)
        out[(size_t)(qb + lg * 4 + r) * DIM + w * 64 + ct * 16 + lr] =
            oacc[ct][r] * linv[r];
  }
}

extern "C" void kernel_launch(void* const* d_in, const int* in_sizes, int n_in,
                              void* d_out, int out_size, void* d_ws, size_t ws_size,
                              hipStream_t stream) {
  (void)in_sizes; (void)n_in; (void)out_size;
  const float* q = (const float*)d_in[0];
  const float* k = (const float*)d_in[1];
  const float* v = (const float*)d_in[2];
  float* out = (float*)d_out;

  const size_t kbf_elems = (size_t)SEQ * DIM;
  const size_t vt_elems  = (size_t)DIM * SEQ;
  const size_t op_elems  = (size_t)SPLITS * SEQ * DIM;
  const size_t ml_elems  = (size_t)SPLITS * SEQ * 2;
  const size_t need = kbf_elems * 2 + vt_elems * 2 + op_elems * 4 + ml_elems * 4;

  if (ws_size >= need) {
    ushort* kbf  = (ushort*)d_ws;
    ushort* vtp  = kbf + kbf_elems;
    float* opart = (float*)(vtp + vt_elems);
    float* ml    = opart + op_elems;

    cvt_bf16<<<(SEQ * DIM / 8 + 255) / 256, 256, 0, stream>>>(k, kbf, SEQ * DIM / 8);
    transpose_tile_bf16<<<(SEQ / 64) * (DIM / 64), 256, 0, stream>>>(v, vtp);
    attn_split<<<(SEQ / BQ) * SPLITS, 512, 0, stream>>>(q, kbf, vtp, opart, ml);
    combine<<<(SEQ * DIM / 4) / 256, 256, 0, stream>>>(opart, ml, out);
  } else {
    attn_fused_fb<<<SEQ / 16, 512, 0, stream>>>(q, k, v, out);
  }
}

// Round 12
// 92.554 us; speedup vs baseline: 1.2930x; 1.2202x over previous
//
#include <hip/hip_runtime.h>
#include <hip/hip_bf16.h>

#define SEQ 4096
#define DIM 512
#define SCALE 0.044194173824159216f  // 1/sqrt(512)

#define SPLITS 4
#define BQ 64
#define KVBLK 64
#define KEYS_PER_SPLIT (SEQ / SPLITS)    // 1024
#define ITERS (KEYS_PER_SPLIT / KVBLK)   // 16
#define THR_DEFER 8.0f

typedef __attribute__((ext_vector_type(8))) short short8;
typedef __attribute__((ext_vector_type(4))) float f32x4;
typedef __attribute__((ext_vector_type(16))) float f32x16;

__device__ __forceinline__ short f2bf(float f) {
  union { float f; unsigned u; } c; c.f = f;
  unsigned u = c.u;
  return (short)((u + 0x7FFFu + ((u >> 16) & 1u)) >> 16);
}

__device__ __forceinline__ short8 pack8(float4 a, float4 b) {
  short8 r;
  r[0] = f2bf(a.x); r[1] = f2bf(a.y); r[2] = f2bf(a.z); r[3] = f2bf(a.w);
  r[4] = f2bf(b.x); r[5] = f2bf(b.y); r[6] = f2bf(b.z); r[7] = f2bf(b.w);
  return r;
}

__device__ __forceinline__ ushort4 pack4(float a, float b, float c, float d) {
  ushort4 r;
  r.x = (unsigned short)f2bf(a); r.y = (unsigned short)f2bf(b);
  r.z = (unsigned short)f2bf(c); r.w = (unsigned short)f2bf(d);
  return r;
}

// async global->LDS, 16B per lane, dest = uniform base + lane*16
__device__ __forceinline__ void gload16(const void* g, void* l) {
  __builtin_amdgcn_global_load_lds(
      (const __attribute__((address_space(1))) unsigned int*)g,
      (__attribute__((address_space(3))) unsigned int*)l, 16, 0, 0);
}

// ---------- prep: fp32 -> bf16 row-major (for K) ----------
__global__ void cvt_bf16(const float* __restrict__ in, ushort* __restrict__ ob, int n8) {
  int i = blockIdx.x * blockDim.x + threadIdx.x;
  if (i >= n8) return;
  const float4* p = (const float4*)(in + (size_t)i * 8);
  short8 v = pack8(p[0], p[1]);
  *(short8*)(ob + (size_t)i * 8) = v;
}

// ---------- prep: fp32 V (S x D) -> bf16 V^T (D x S) ----------
__global__ void transpose_bf16(const float* __restrict__ v, ushort* __restrict__ vt) {
  __shared__ float t[64][65];
  const int bs = blockIdx.x % (SEQ / 64);
  const int bd = blockIdx.x / (SEQ / 64);
  const int s0 = bs * 64, d0 = bd * 64;
  const int tid = threadIdx.x;
#pragma unroll
  for (int k = 0; k < 16; ++k) {
    int idx = k * 256 + tid;
    int r = idx >> 6, c = idx & 63;
    t[r][c] = v[(size_t)(s0 + r) * DIM + d0 + c];
  }
  __syncthreads();
#pragma unroll
  for (int k = 0; k < 16; ++k) {
    int idx = k * 256 + tid;
    int dr = idx >> 6, sc = idx & 63;
    vt[(size_t)(d0 + dr) * SEQ + s0 + sc] = (ushort)f2bf(t[sc][dr]);
  }
}

// ---------- fused attention (round-6 schedule; PV dedup: wave-exclusive cols) ----------
// QK role:  rg = w&3 (16 q-rows), kh = w>>2 (32-key half). Swapped QK^T
//           (mfma(K,Q) -> S^T) => in-register softmax; cross-kh max merge
//           via tiny mx_st LDS exchange (folded into existing barrier).
// PV role:  wave w -> ALL 64 q-rows, cols w*64..+64 (vtt reads wave-exclusive),
//           32x32x16 MFMA, A=P from p_lds, B=V from vtt. O = 4 x f32x16.
__global__ __launch_bounds__(512, 2) void attn_split(
    const float* __restrict__ q, const ushort* __restrict__ kbf,
    const ushort* __restrict__ vt, float* __restrict__ opart,
    float* __restrict__ ml) {
  __shared__ __align__(16) ushort kt[KVBLK * DIM];    // 64 KB, granule16 ^= row&31
  __shared__ __align__(16) ushort vtt[DIM * KVBLK];   // 64 KB, granule16 ^= row&7
  __shared__ __align__(16) ushort p_lds[BQ * KVBLK];  // 8 KB,  byte ^= (row&7)<<4
  __shared__ float mx_st[2][BQ];                      // per-kh tile max exchange
  __shared__ float osc_st[BQ];                        // per-row rescale factor
  __shared__ float l_st[2][BQ];                       // epilogue l merge
  __shared__ int   flag_st[4];                        // per 16-row strip: rescaled?

  const int tid  = threadIdx.x;
  const int lane = tid & 63;
  const int w    = tid >> 6;
  const int lr   = lane & 15;
  const int lg   = lane >> 4;
  const int l31  = lane & 31;
  const int hi   = lane >> 5;
  const int sp   = blockIdx.x & (SPLITS - 1);
  const int qb   = blockIdx.x >> 2;
  const int rg   = w & 3;    // QK row-group (16 rows)
  const int kh   = w >> 2;   // QK key-half (32 keys)
  const int qrow0 = qb * BQ;
  const int kbase = sp * KEYS_PER_SPLIT;

  // Q fragments (B-operand 16x16x32): col=qrow=lr, k=lg*8+j
  short8 qf[16];
  {
    const float* qp = q + (size_t)(qrow0 + rg * 16 + lr) * DIM + lg * 8;
#pragma unroll
    for (int c = 0; c < 16; ++c)
      qf[c] = pack8(*(const float4*)(qp + c * 32), *(const float4*)(qp + c * 32 + 4));
  }
  f32x16 oacc[4] = {};  // [rt*2+dt]: rows rt*32..+32, cols w*64+dt*32..+32
  float m_reg = -INFINITY, l_reg = 0.f;

  // K rows 1KB: LDS[r][g16] = K[kb+r][(g16 ^ (r&31))*8..]; 8 gloads/wave
  auto stageK = [&](int kb) {
#pragma unroll
    for (int i = 0; i < 8; ++i) {
      int r = w * 8 + i;
      const ushort* src = kbf + (size_t)(kb + r) * DIM + ((lane ^ (r & 31)) * 8);
      gload16(src, &kt[r * DIM]);
    }
  };
  // V^T rows 128B: LDS[d][g] = vt[d][kb + ((g^(d&7))*8)..]; 8 gloads/wave
  auto stageV = [&](int kb) {
#pragma unroll
    for (int j = 0; j < 8; ++j) {
      int r0 = w * 64 + j * 8;
      int rr = r0 + (lane >> 3);
      const ushort* src = vt + (size_t)rr * SEQ + kb + (((lane & 7) ^ (rr & 7)) * 8);
      gload16(src, &vtt[r0 * KVBLK]);
    }
  };

  stageK(kbase);  // K(0) in flight

#pragma unroll 1
  for (int it = 0; it < ITERS; ++it) {
    const int kb = kbase + it * KVBLK;

    stageV(kb);  // V(t) in flight; lands during QK/softmax
    asm volatile("s_waitcnt vmcnt(8)" ::: "memory");  // K(t) landed (V=8 out)
    __builtin_amdgcn_s_barrier();                     // bar-A: kt(t) ready

    // ---- swapped QK^T (16x16x32): S^T[key][qrow] for wave's 32 keys ----
    f32x4 s0 = {}, s1 = {};
    {
      const int kr0 = kh * 32 + lr;
      const int kr1 = kr0 + 16;
      const char* kb0 = (const char*)kt + kr0 * 1024;
      const char* kb1 = (const char*)kt + kr1 * 1024;
      const int sw0 = kr0 & 31, sw1 = kr1 & 31;
      __builtin_amdgcn_s_setprio(1);
#pragma unroll
      for (int c = 0; c < 16; ++c) {
        short8 k0 = *(const short8*)(kb0 + (((c * 4 + lg) ^ sw0) << 4));
        short8 k1 = *(const short8*)(kb1 + (((c * 4 + lg) ^ sw1) << 4));
        s0 = __builtin_amdgcn_mfma_f32_16x16x32_bf16(k0, qf[c], s0, 0, 0, 0);
        s1 = __builtin_amdgcn_mfma_f32_16x16x32_bf16(k1, qf[c], s1, 0, 0, 0);
      }
      __builtin_amdgcn_s_setprio(0);
    }

    // per-row tile max over wave's 32 keys (lane owns qrow=lr)
    float sc0[4], sc1[4];
#pragma unroll
    for (int r = 0; r < 4; ++r) { sc0[r] = s0[r] * SCALE; sc1[r] = s1[r] * SCALE; }
    float tmax = fmaxf(fmaxf(fmaxf(sc0[0], sc0[1]), fmaxf(sc0[2], sc0[3])),
                       fmaxf(fmaxf(sc1[0], sc1[1]), fmaxf(sc1[2], sc1[3])));
    tmax = fmaxf(tmax, __shfl_xor(tmax, 16));
    tmax = fmaxf(tmax, __shfl_xor(tmax, 32));
    if (lane < 16) mx_st[kh][rg * 16 + lane] = tmax;

    asm volatile("s_waitcnt lgkmcnt(0)" ::: "memory");
    __builtin_amdgcn_s_barrier();                     // bar-B: kt consumed, mx visible

    if (it + 1 < ITERS) stageK(kb + KVBLK);  // K(t+1) lands during PV

    // ---- softmax finish: common m across kh pair, defer-max, P -> LDS ----
    {
      const int row = rg * 16 + lr;
      float tmax64 = fmaxf(mx_st[0][row], mx_st[1][row]);
      bool resc = tmax64 > m_reg + THR_DEFER;
      float mnew = resc ? tmax64 : m_reg;
      float osc = __expf(m_reg - mnew);  // 1.0 when deferred; 0 on first tile
      unsigned long long bl = __ballot(resc);
      if (kh == 0 && lane == 0) flag_st[rg] = (bl != 0ull) ? 1 : 0;
      if (kh == 0 && lane < 16) osc_st[row] = osc;
      m_reg = mnew;
      l_reg *= osc;
      float p0[4], p1[4];
#pragma unroll
      for (int r = 0; r < 4; ++r) {
        p0[r] = __expf(sc0[r] - m_reg);
        p1[r] = __expf(sc1[r] - m_reg);
      }
      float ps = ((p0[0] + p0[1]) + (p0[2] + p0[3])) +
                 ((p1[0] + p1[1]) + (p1[2] + p1[3]));
      ps += __shfl_xor(ps, 16);
      ps += __shfl_xor(ps, 32);
      l_reg += ps;
      // P write: row=qrow, keys kh*32+lg*4+r (+16 for s1); swizzle (row&7)<<4
      char* pb = (char*)p_lds + row * 128;
      const int sw = (row & 7) << 4;
      const int off = kh * 64 + lg * 8;
      *(ushort4*)(pb + (off ^ sw))        = pack4(p0[0], p0[1], p0[2], p0[3]);
      *(ushort4*)(pb + ((off + 32) ^ sw)) = pack4(p1[0], p1[1], p1[2], p1[3]);
    }

    if (it + 1 < ITERS) {
      asm volatile("s_waitcnt vmcnt(8)" ::: "memory");  // V(t) landed (K(t+1)=8 out)
    } else {
      asm volatile("s_waitcnt vmcnt(0)" ::: "memory");  // drain V(t)
    }
    asm volatile("s_waitcnt lgkmcnt(0)" ::: "memory");  // p_lds/osc/flag visible
    __builtin_amdgcn_s_barrier();                       // bar-C

    // ---- PV (32x32x16): ALL 64 rows, cols w*64..+64 (wave-exclusive vtt) ----
    {
#pragma unroll
      for (int rt = 0; rt < 2; ++rt) {
        if (flag_st[rt * 2] | flag_st[rt * 2 + 1]) {
          float ov[16];
#pragma unroll
          for (int r = 0; r < 16; ++r)
            ov[r] = osc_st[rt * 32 + (r & 3) + 8 * (r >> 2) + 4 * hi];
#pragma unroll
          for (int dt = 0; dt < 2; ++dt)
#pragma unroll
            for (int r = 0; r < 16; ++r) oacc[rt * 2 + dt][r] *= ov[r];
        }
      }
      __builtin_amdgcn_s_setprio(1);
#pragma unroll
      for (int c = 0; c < 4; ++c)
#pragma unroll
        for (int rt = 0; rt < 2; ++rt) {
          const int arow = rt * 32 + l31;
          short8 pa = *(const short8*)((const char*)p_lds + arow * 128 +
                                       ((c * 32 + hi * 16) ^ ((arow & 7) << 4)));
#pragma unroll
          for (int dt = 0; dt < 2; ++dt) {
            int vrow = w * 64 + dt * 32 + l31;
            short8 vf = *(const short8*)((const char*)vtt + vrow * 128 +
                                         ((c * 32 + hi * 16) ^ ((vrow & 7) << 4)));
            oacc[rt * 2 + dt] = __builtin_amdgcn_mfma_f32_32x32x16_bf16(
                pa, vf, oacc[rt * 2 + dt], 0, 0, 0);
          }
        }
      __builtin_amdgcn_s_setprio(0);
    }
    asm volatile("s_waitcnt lgkmcnt(0)" ::: "memory");  // vtt/p reads done
    __builtin_amdgcn_s_barrier();                       // bar-D: vtt free
  }

  // ---- epilogue: merge l across kh, write opart + ml ----
  if (lane < 16) {
    l_st[kh][rg * 16 + lane] = l_reg;
    if (kh == 0) mx_st[0][rg * 16 + lane] = m_reg;
  }
  __syncthreads();
  {
    float* op = opart + ((size_t)sp * SEQ + qrow0) * DIM + w * 64;
#pragma unroll
    for (int rt = 0; rt < 2; ++rt)
#pragma unroll
      for (int dt = 0; dt < 2; ++dt)
#pragma unroll
        for (int r = 0; r < 16; ++r) {
          int crow = rt * 32 + (r & 3) + 8 * (r >> 2) + 4 * hi;
          op[(size_t)crow * DIM + dt * 32 + l31] = oacc[rt * 2 + dt][r];
        }
  }
  if (tid < BQ) {
    size_t base = ((size_t)sp * SEQ + qrow0 + tid) * 2;
    ml[base]     = mx_st[0][tid];
    ml[base + 1] = l_st[0][tid] + l_st[1][tid];
  }
}

// ---------- combine split partials ----------
__global__ void combine(const float* __restrict__ opart, const float* __restrict__ ml,
                        float* __restrict__ out) {
  int gid = blockIdx.x * 256 + threadIdx.x;
  int row = gid >> 7;
  int dv  = (gid & 127) * 4;
  float m[SPLITS], l[SPLITS], wgt[SPLITS];
  float M = -INFINITY;
#pragma unroll
  for (int i = 0; i < SPLITS; ++i) {
    m[i] = ml[((size_t)i * SEQ + row) * 2];
    l[i] = ml[((size_t)i * SEQ + row) * 2 + 1];
    M = fmaxf(M, m[i]);
  }
  float L = 0.f;
#pragma unroll
  for (int i = 0; i < SPLITS; ++i) { wgt[i] = __expf(m[i] - M); L += l[i] * wgt[i]; }
  float inv = 1.f / L;
  float4 acc = {0.f, 0.f, 0.f, 0.f};
#pragma unroll
  for (int i = 0; i < SPLITS; ++i) {
    float4 o = *(const float4*)(opart + ((size_t)i * SEQ + row) * DIM + dv);
    acc.x += o.x * wgt[i]; acc.y += o.y * wgt[i];
    acc.z += o.z * wgt[i]; acc.w += o.w * wgt[i];
  }
  acc.x *= inv; acc.y *= inv; acc.z *= inv; acc.w *= inv;
  *(float4*)(out + (size_t)row * DIM + dv) = acc;
}

// ---------- fallback if ws too small ----------
__global__ __launch_bounds__(512) void attn_fused_fb(
    const float* __restrict__ q, const float* __restrict__ k,
    const float* __restrict__ v, float* __restrict__ out) {
  __shared__ float s_lds[16][128];
  __shared__ __align__(16) unsigned short p_lds[16 * 128];
  __shared__ float m_st[16], l_st[16], osc_st[16];
  const int tid = threadIdx.x, lane = tid & 63, w = tid >> 6;
  const int lr = lane & 15, lg = lane >> 4, qb = blockIdx.x * 16;
  if (tid < 16) { m_st[tid] = -INFINITY; l_st[tid] = 0.f; }
  short8 qf[16];
  {
    const float* qp = q + (size_t)(qb + lr) * DIM + lg * 8;
#pragma unroll
    for (int c = 0; c < 16; ++c)
      qf[c] = pack8(*(const float4*)(qp + c * 32), *(const float4*)(qp + c * 32 + 4));
  }
  f32x4 oacc[4] = {};
  __syncthreads();
  for (int it = 0; it < SEQ / 128; ++it) {
    const int kb = it * 128;
    {
      const float* kp = k + (size_t)(kb + w * 16 + lr) * DIM + lg * 8;
      f32x4 sacc = {};
#pragma unroll
      for (int c = 0; c < 16; ++c) {
        short8 kf = pack8(*(const float4*)(kp + c * 32), *(const float4*)(kp + c * 32 + 4));
        sacc = __builtin_amdgcn_mfma_f32_16x16x32_bf16(qf[c], kf, sacc, 0, 0, 0);
      }
#pragma unroll
      for (int r = 0; r < 4; ++r) s_lds[lg * 4 + r][w * 16 + lr] = sacc[r] * SCALE;
    }
    __syncthreads();
    {
      const int srow = tid >> 5, sj = tid & 31;
      float4 sv = *(const float4*)&s_lds[srow][sj * 4];
      float tmax = fmaxf(fmaxf(sv.x, sv.y), fmaxf(sv.z, sv.w));
#pragma unroll
      for (int m = 16; m >= 1; m >>= 1) tmax = fmaxf(tmax, __shfl_xor(tmax, m));
      float mold = m_st[srow], mnew = fmaxf(mold, tmax);
      float p0 = __expf(sv.x - mnew), p1 = __expf(sv.y - mnew);
      float p2 = __expf(sv.z - mnew), p3 = __expf(sv.w - mnew);
      float psum = (p0 + p1) + (p2 + p3);
#pragma unroll
      for (int m = 16; m >= 1; m >>= 1) psum += __shfl_xor(psum, m);
      if (sj == 0) {
        float sc = __expf(mold - mnew);
        l_st[srow] = l_st[srow] * sc + psum; m_st[srow] = mnew; osc_st[srow] = sc;
      }
      ushort4 pb;
      pb.x = (unsigned short)f2bf(p0); pb.y = (unsigned short)f2bf(p1);
      pb.z = (unsigned short)f2bf(p2); pb.w = (unsigned short)f2bf(p3);
      int lin = srow * 256 + sj * 8;
      *(ushort4*)((char*)p_lds + (lin ^ ((srow & 7) << 4))) = pb;
    }
    __syncthreads();
    {
      float osc[4];
#pragma unroll
      for (int r = 0; r < 4; ++r) osc[r] = osc_st[lg * 4 + r];
#pragma unroll
      for (int ct = 0; ct < 4; ++ct)
#pragma unroll
        for (int r = 0; r < 4; ++r) oacc[ct][r] *= osc[r];
#pragma unroll
      for (int kc = 0; kc < 4; ++kc) {
        int lin = lr * 256 + (kc * 32 + 8 * lg) * 2;
        short8 pf = *(const short8*)((const char*)p_lds + (lin ^ ((lr & 7) << 4)));
        const float* vp0 = v + (size_t)(kb + kc * 32 + 8 * lg) * DIM + w * 64 + lr;
#pragma unroll
        for (int ct = 0; ct < 4; ++ct) {
          const float* vp = vp0 + ct * 16;
          short8 vf;
#pragma unroll
          for (int jj = 0; jj < 8; ++jj) vf[jj] = f2bf(vp[(size_t)jj * DIM]);
          oacc[ct] = __builtin_amdgcn_mfma_f32_16x16x32_bf16(pf, vf, oacc[ct], 0, 0, 0);
        }
      }
    }
    __syncthreads();
  }
  {
    float linv[4];
#pragma unroll
    for (int r = 0; r < 4; ++r) linv[r] = 1.f / l_st[lg * 4 + r];
#pragma unroll
    for (int ct = 0; ct < 4; ++ct)
#pragma unroll
      for (int r = 0; r < 4; ++r)
        out[(size_t)(qb + lg * 4 + r) * DIM + w * 64 + ct * 16 + lr] =
            oacc[ct][r] * linv[r];
  }
}

extern "C" void kernel_launch(void* const* d_in, const int* in_sizes, int n_in,
                              void* d_out, int out_size, void* d_ws, size_t ws_size,
                              hipStream_t stream) {
  (void)in_sizes; (void)n_in; (void)out_size;
  const float* q = (const float*)d_in[0];
  const float* k = (const float*)d_in[1];
  const float* v = (const float*)d_in[2];
  float* out = (float*)d_out;

  const size_t kbf_elems = (size_t)SEQ * DIM;
  const size_t vt_elems  = (size_t)DIM * SEQ;
  const size_t op_elems  = (size_t)SPLITS * SEQ * DIM;
  const size_t ml_elems  = (size_t)SPLITS * SEQ * 2;
  const size_t need = kbf_elems * 2 + vt_elems * 2 + op_elems * 4 + ml_elems * 4;

  if (ws_size >= need) {
    ushort* kbf  = (ushort*)d_ws;
    ushort* vtb  = kbf + kbf_elems;
    float* opart = (float*)(vtb + vt_elems);
    float* ml    = opart + op_elems;

    cvt_bf16<<<(SEQ * DIM / 8 + 255) / 256, 256, 0, stream>>>(k, kbf, SEQ * DIM / 8);
    transpose_bf16<<<(SEQ / 64) * (DIM / 64), 256, 0, stream>>>(v, vtb);
    attn_split<<<(SEQ / BQ) * SPLITS, 512, 0, stream>>>(q, kbf, vtb, opart, ml);
    combine<<<(SEQ * DIM / 4) / 256, 256, 0, stream>>>(opart, ml, out);
  } else {
    attn_fused_fb<<<SEQ / 16, 512, 0, stream>>>(q, k, v, out);
  }
}

// Round 13
// 87.037 us; speedup vs baseline: 1.3750x; 1.0634x over previous
//
#include <hip/hip_runtime.h>
#include <hip/hip_bf16.h>

#define SEQ 4096
#define DIM 512
#define SCALE 0.044194173824159216f  // 1/sqrt(512)

#define SPLITS 4
#define BQ 64
#define KVBLK 64
#define KEYS_PER_SPLIT (SEQ / SPLITS)    // 1024
#define ITERS (KEYS_PER_SPLIT / KVBLK)   // 16
#define THR_DEFER 8.0f

typedef __attribute__((ext_vector_type(8))) short short8;
typedef __attribute__((ext_vector_type(4))) float f32x4;
typedef __attribute__((ext_vector_type(16))) float f32x16;

__device__ __forceinline__ short f2bf(float f) {
  union { float f; unsigned u; } c; c.f = f;
  unsigned u = c.u;
  return (short)((u + 0x7FFFu + ((u >> 16) & 1u)) >> 16);
}

__device__ __forceinline__ short8 pack8(float4 a, float4 b) {
  short8 r;
  r[0] = f2bf(a.x); r[1] = f2bf(a.y); r[2] = f2bf(a.z); r[3] = f2bf(a.w);
  r[4] = f2bf(b.x); r[5] = f2bf(b.y); r[6] = f2bf(b.z); r[7] = f2bf(b.w);
  return r;
}

__device__ __forceinline__ ushort4 pack4(float a, float b, float c, float d) {
  ushort4 r;
  r.x = (unsigned short)f2bf(a); r.y = (unsigned short)f2bf(b);
  r.z = (unsigned short)f2bf(c); r.w = (unsigned short)f2bf(d);
  return r;
}

// async global->LDS, 16B per lane, dest = uniform base + lane*16
__device__ __forceinline__ void gload16(const void* g, void* l) {
  __builtin_amdgcn_global_load_lds(
      (const __attribute__((address_space(1))) unsigned int*)g,
      (__attribute__((address_space(3))) unsigned int*)l, 16, 0, 0);
}

// ---------- prep: fp32 -> bf16 row-major (for K) ----------
__global__ void cvt_bf16(const float* __restrict__ in, ushort* __restrict__ ob, int n8) {
  int i = blockIdx.x * blockDim.x + threadIdx.x;
  if (i >= n8) return;
  const float4* p = (const float4*)(in + (size_t)i * 8);
  short8 v = pack8(p[0], p[1]);
  *(short8*)(ob + (size_t)i * 8) = v;
}

// ---------- prep: fp32 V (S x D) -> bf16 V^T (D x S) ----------
__global__ void transpose_bf16(const float* __restrict__ v, ushort* __restrict__ vt) {
  __shared__ float t[64][65];
  const int bs = blockIdx.x % (SEQ / 64);
  const int bd = blockIdx.x / (SEQ / 64);
  const int s0 = bs * 64, d0 = bd * 64;
  const int tid = threadIdx.x;
#pragma unroll
  for (int k = 0; k < 16; ++k) {
    int idx = k * 256 + tid;
    int r = idx >> 6, c = idx & 63;
    t[r][c] = v[(size_t)(s0 + r) * DIM + d0 + c];
  }
  __syncthreads();
#pragma unroll
  for (int k = 0; k < 16; ++k) {
    int idx = k * 256 + tid;
    int dr = idx >> 6, sc = idx & 63;
    vt[(size_t)(d0 + dr) * SEQ + s0 + sc] = (ushort)f2bf(t[sc][dr]);
  }
}

// ---------- fused attention (round-6 structure, bar-D removed: 3 barriers/iter) ----------
// QK role:  rg = w&3 (16 q-rows), kh = w>>2 (32-key half). Swapped QK^T
//           (mfma(K,Q) -> S^T) => in-register softmax; cross-kh max merge
//           via mx_st LDS exchange (folded into bar-B).
// PV role:  rg_pv = w&1 (32 q-rows), cg = w>>1 (128 out cols), 32x32x16 MFMA.
// Per iter: vmcnt(0) -> BAR-A (kt(t) ready; all PV(t-1) vtt reads done)
//           -> stageV(t) -> QK(t) -> lgkm -> BAR-B -> stageK(t+1) -> SM(t)
//           -> vmcnt(8) lgkm -> BAR-C -> PV(t)
__global__ __launch_bounds__(512, 2) void attn_split(
    const float* __restrict__ q, const ushort* __restrict__ kbf,
    const ushort* __restrict__ vt, float* __restrict__ opart,
    float* __restrict__ ml) {
  __shared__ __align__(16) ushort kt[KVBLK * DIM];    // 64 KB, granule16 ^= row&31
  __shared__ __align__(16) ushort vtt[DIM * KVBLK];   // 64 KB, granule16 ^= row&7
  __shared__ __align__(16) ushort p_lds[BQ * KVBLK];  // 8 KB,  byte ^= (row&7)<<4
  __shared__ float mx_st[2][BQ];                      // per-kh tile max exchange
  __shared__ float osc_st[BQ];                        // per-row rescale factor
  __shared__ float l_st[2][BQ];                       // epilogue l merge
  __shared__ int   flag_st[4];                        // per 16-row strip: rescaled?

  const int tid  = threadIdx.x;
  const int lane = tid & 63;
  const int w    = tid >> 6;
  const int lr   = lane & 15;
  const int lg   = lane >> 4;
  const int l31  = lane & 31;
  const int hi   = lane >> 5;
  const int sp   = blockIdx.x & (SPLITS - 1);
  const int qb   = blockIdx.x >> 2;
  const int rg   = w & 3;    // QK row-group (16 rows)
  const int kh   = w >> 2;   // QK key-half (32 keys)
  const int rg_pv = w & 1;   // PV row-group (32 rows)
  const int cg    = w >> 1;  // PV col-group (128 cols)
  const int qrow0 = qb * BQ;
  const int kbase = sp * KEYS_PER_SPLIT;

  // Q fragments (B-operand 16x16x32): col=qrow=lr, k=lg*8+j
  short8 qf[16];
  {
    const float* qp = q + (size_t)(qrow0 + rg * 16 + lr) * DIM + lg * 8;
#pragma unroll
    for (int c = 0; c < 16; ++c)
      qf[c] = pack8(*(const float4*)(qp + c * 32), *(const float4*)(qp + c * 32 + 4));
  }
  f32x16 oacc[4] = {};
  float m_reg = -INFINITY, l_reg = 0.f;

  // K rows 1KB: LDS[r][g16] = K[kb+r][(g16 ^ (r&31))*8..]; 8 gloads/wave
  auto stageK = [&](int kb) {
#pragma unroll
    for (int i = 0; i < 8; ++i) {
      int r = w * 8 + i;
      const ushort* src = kbf + (size_t)(kb + r) * DIM + ((lane ^ (r & 31)) * 8);
      gload16(src, &kt[r * DIM]);
    }
  };
  // V^T rows 128B: LDS[d][g] = vt[d][kb + ((g^(d&7))*8)..]; 8 gloads/wave
  auto stageV = [&](int kb) {
#pragma unroll
    for (int j = 0; j < 8; ++j) {
      int r0 = w * 64 + j * 8;
      int rr = r0 + (lane >> 3);
      const ushort* src = vt + (size_t)rr * SEQ + kb + (((lane & 7) ^ (rr & 7)) * 8);
      gload16(src, &vtt[r0 * KVBLK]);
    }
  };

  stageK(kbase);  // K(0) in flight

#pragma unroll 1
  for (int it = 0; it < ITERS; ++it) {
    const int kb = kbase + it * KVBLK;

    asm volatile("s_waitcnt vmcnt(0)" ::: "memory");  // K(t) landed (only K in queue)
    __builtin_amdgcn_s_barrier();  // bar-A: kt(t) ready; all PV(t-1) vtt reads done

    stageV(kb);  // V(t) -> vtt, safe post-bar-A; lands during QK/SM

    // ---- swapped QK^T (16x16x32): S^T[key][qrow] for wave's 32 keys ----
    f32x4 s0 = {}, s1 = {};
    {
      const int kr0 = kh * 32 + lr;
      const int kr1 = kr0 + 16;
      const char* kb0 = (const char*)kt + kr0 * 1024;
      const char* kb1 = (const char*)kt + kr1 * 1024;
      const int sw0 = kr0 & 31, sw1 = kr1 & 31;
      __builtin_amdgcn_s_setprio(1);
#pragma unroll
      for (int c = 0; c < 16; ++c) {
        short8 k0 = *(const short8*)(kb0 + (((c * 4 + lg) ^ sw0) << 4));
        short8 k1 = *(const short8*)(kb1 + (((c * 4 + lg) ^ sw1) << 4));
        s0 = __builtin_amdgcn_mfma_f32_16x16x32_bf16(k0, qf[c], s0, 0, 0, 0);
        s1 = __builtin_amdgcn_mfma_f32_16x16x32_bf16(k1, qf[c], s1, 0, 0, 0);
      }
      __builtin_amdgcn_s_setprio(0);
    }

    // per-row tile max over wave's 32 keys (lane owns qrow=lr)
    float sc0[4], sc1[4];
#pragma unroll
    for (int r = 0; r < 4; ++r) { sc0[r] = s0[r] * SCALE; sc1[r] = s1[r] * SCALE; }
    float tmax = fmaxf(fmaxf(fmaxf(sc0[0], sc0[1]), fmaxf(sc0[2], sc0[3])),
                       fmaxf(fmaxf(sc1[0], sc1[1]), fmaxf(sc1[2], sc1[3])));
    tmax = fmaxf(tmax, __shfl_xor(tmax, 16));
    tmax = fmaxf(tmax, __shfl_xor(tmax, 32));
    if (lane < 16) mx_st[kh][rg * 16 + lane] = tmax;

    asm volatile("s_waitcnt lgkmcnt(0)" ::: "memory");
    __builtin_amdgcn_s_barrier();                     // bar-B: kt consumed, mx visible

    if (it + 1 < ITERS) stageK(kb + KVBLK);  // K(t+1) lands during PV

    // ---- softmax finish: common m across kh pair, defer-max, P -> LDS ----
    {
      const int row = rg * 16 + lr;
      float tmax64 = fmaxf(mx_st[0][row], mx_st[1][row]);
      bool resc = tmax64 > m_reg + THR_DEFER;
      float mnew = resc ? tmax64 : m_reg;
      float osc = __expf(m_reg - mnew);  // 1.0 when deferred; 0 on first tile
      unsigned long long bl = __ballot(resc);
      if (kh == 0 && lane == 0) flag_st[rg] = (bl != 0ull) ? 1 : 0;
      if (kh == 0 && lane < 16) osc_st[row] = osc;
      m_reg = mnew;
      l_reg *= osc;
      float p0[4], p1[4];
#pragma unroll
      for (int r = 0; r < 4; ++r) {
        p0[r] = __expf(sc0[r] - m_reg);
        p1[r] = __expf(sc1[r] - m_reg);
      }
      float ps = ((p0[0] + p0[1]) + (p0[2] + p0[3])) +
                 ((p1[0] + p1[1]) + (p1[2] + p1[3]));
      ps += __shfl_xor(ps, 16);
      ps += __shfl_xor(ps, 32);
      l_reg += ps;
      // P write: row=qrow, keys kh*32+lg*4+r (+16 for s1); swizzle (row&7)<<4
      char* pb = (char*)p_lds + row * 128;
      const int sw = (row & 7) << 4;
      const int off = kh * 64 + lg * 8;
      *(ushort4*)(pb + (off ^ sw))        = pack4(p0[0], p0[1], p0[2], p0[3]);
      *(ushort4*)(pb + ((off + 32) ^ sw)) = pack4(p1[0], p1[1], p1[2], p1[3]);
    }

    if (it + 1 < ITERS) {
      asm volatile("s_waitcnt vmcnt(8)" ::: "memory");  // V(t) landed (K(t+1)=8 out)
    } else {
      asm volatile("s_waitcnt vmcnt(0)" ::: "memory");  // drain V(t)
    }
    asm volatile("s_waitcnt lgkmcnt(0)" ::: "memory");  // p_lds/osc/flag visible
    __builtin_amdgcn_s_barrier();                       // bar-C

    // ---- PV (32x32x16): rows rg_pv*32.., cols cg*128.. ----
    {
      if (flag_st[rg_pv * 2] | flag_st[rg_pv * 2 + 1]) {
        float ov[16];
#pragma unroll
        for (int r = 0; r < 16; ++r)
          ov[r] = osc_st[rg_pv * 32 + (r & 3) + 8 * (r >> 2) + 4 * hi];
#pragma unroll
        for (int t = 0; t < 4; ++t)
#pragma unroll
          for (int r = 0; r < 16; ++r) oacc[t][r] *= ov[r];
      }
      const int arow = rg_pv * 32 + l31;
      const char* prow = (const char*)p_lds + arow * 128;
      const int psw = (arow & 7) << 4;
      __builtin_amdgcn_s_setprio(1);
#pragma unroll
      for (int c = 0; c < 4; ++c) {
        short8 pa = *(const short8*)(prow + ((c * 32 + hi * 16) ^ psw));
#pragma unroll
        for (int t = 0; t < 4; ++t) {
          int vrow = cg * 128 + t * 32 + l31;
          short8 vf = *(const short8*)((const char*)vtt + vrow * 128 +
                                       ((c * 32 + hi * 16) ^ ((vrow & 7) << 4)));
          oacc[t] = __builtin_amdgcn_mfma_f32_32x32x16_bf16(pa, vf, oacc[t], 0, 0, 0);
        }
      }
      __builtin_amdgcn_s_setprio(0);
    }
    // no bar-D: bar-A of next iter covers vtt reuse
  }

  // ---- epilogue: merge l across kh, write opart + ml ----
  if (lane < 16) {
    l_st[kh][rg * 16 + lane] = l_reg;
    if (kh == 0) mx_st[0][rg * 16 + lane] = m_reg;
  }
  __syncthreads();
  {
    float* op = opart + ((size_t)sp * SEQ + qrow0 + rg_pv * 32) * DIM + cg * 128;
#pragma unroll
    for (int t = 0; t < 4; ++t)
#pragma unroll
      for (int r = 0; r < 16; ++r) {
        int crow = (r & 3) + 8 * (r >> 2) + 4 * hi;
        op[(size_t)crow * DIM + t * 32 + l31] = oacc[t][r];
      }
  }
  if (tid < BQ) {
    size_t base = ((size_t)sp * SEQ + qrow0 + tid) * 2;
    ml[base]     = mx_st[0][tid];
    ml[base + 1] = l_st[0][tid] + l_st[1][tid];
  }
}

// ---------- combine split partials ----------
__global__ void combine(const float* __restrict__ opart, const float* __restrict__ ml,
                        float* __restrict__ out) {
  int gid = blockIdx.x * 256 + threadIdx.x;
  int row = gid >> 7;
  int dv  = (gid & 127) * 4;
  float m[SPLITS], l[SPLITS], wgt[SPLITS];
  float M = -INFINITY;
#pragma unroll
  for (int i = 0; i < SPLITS; ++i) {
    m[i] = ml[((size_t)i * SEQ + row) * 2];
    l[i] = ml[((size_t)i * SEQ + row) * 2 + 1];
    M = fmaxf(M, m[i]);
  }
  float L = 0.f;
#pragma unroll
  for (int i = 0; i < SPLITS; ++i) { wgt[i] = __expf(m[i] - M); L += l[i] * wgt[i]; }
  float inv = 1.f / L;
  float4 acc = {0.f, 0.f, 0.f, 0.f};
#pragma unroll
  for (int i = 0; i < SPLITS; ++i) {
    float4 o = *(const float4*)(opart + ((size_t)i * SEQ + row) * DIM + dv);
    acc.x += o.x * wgt[i]; acc.y += o.y * wgt[i];
    acc.z += o.z * wgt[i]; acc.w += o.w * wgt[i];
  }
  acc.x *= inv; acc.y *= inv; acc.z *= inv; acc.w *= inv;
  *(float4*)(out + (size_t)row * DIM + dv) = acc;
}

// ---------- fallback if ws too small ----------
__global__ __launch_bounds__(512) void attn_fused_fb(
    const float* __restrict__ q, const float* __restrict__ k,
    const float* __restrict__ v, float* __restrict__ out) {
  __shared__ float s_lds[16][128];
  __shared__ __align__(16) unsigned short p_lds[16 * 128];
  __shared__ float m_st[16], l_st[16], osc_st[16];
  const int tid = threadIdx.x, lane = tid & 63, w = tid >> 6;
  const int lr = lane & 15, lg = lane >> 4, qb = blockIdx.x * 16;
  if (tid < 16) { m_st[tid] = -INFINITY; l_st[tid] = 0.f; }
  short8 qf[16];
  {
    const float* qp = q + (size_t)(qb + lr) * DIM + lg * 8;
#pragma unroll
    for (int c = 0; c < 16; ++c)
      qf[c] = pack8(*(const float4*)(qp + c * 32), *(const float4*)(qp + c * 32 + 4));
  }
  f32x4 oacc[4] = {};
  __syncthreads();
  for (int it = 0; it < SEQ / 128; ++it) {
    const int kb = it * 128;
    {
      const float* kp = k + (size_t)(kb + w * 16 + lr) * DIM + lg * 8;
      f32x4 sacc = {};
#pragma unroll
      for (int c = 0; c < 16; ++c) {
        short8 kf = pack8(*(const float4*)(kp + c * 32), *(const float4*)(kp + c * 32 + 4));
        sacc = __builtin_amdgcn_mfma_f32_16x16x32_bf16(qf[c], kf, sacc, 0, 0, 0);
      }
#pragma unroll
      for (int r = 0; r < 4; ++r) s_lds[lg * 4 + r][w * 16 + lr] = sacc[r] * SCALE;
    }
    __syncthreads();
    {
      const int srow = tid >> 5, sj = tid & 31;
      float4 sv = *(const float4*)&s_lds[srow][sj * 4];
      float tmax = fmaxf(fmaxf(sv.x, sv.y), fmaxf(sv.z, sv.w));
#pragma unroll
      for (int m = 16; m >= 1; m >>= 1) tmax = fmaxf(tmax, __shfl_xor(tmax, m));
      float mold = m_st[srow], mnew = fmaxf(mold, tmax);
      float p0 = __expf(sv.x - mnew), p1 = __expf(sv.y - mnew);
      float p2 = __expf(sv.z - mnew), p3 = __expf(sv.w - mnew);
      float psum = (p0 + p1) + (p2 + p3);
#pragma unroll
      for (int m = 16; m >= 1; m >>= 1) psum += __shfl_xor(psum, m);
      if (sj == 0) {
        float sc = __expf(mold - mnew);
        l_st[srow] = l_st[srow] * sc + psum; m_st[srow] = mnew; osc_st[srow] = sc;
      }
      ushort4 pb;
      pb.x = (unsigned short)f2bf(p0); pb.y = (unsigned short)f2bf(p1);
      pb.z = (unsigned short)f2bf(p2); pb.w = (unsigned short)f2bf(p3);
      int lin = srow * 256 + sj * 8;
      *(ushort4*)((char*)p_lds + (lin ^ ((srow & 7) << 4))) = pb;
    }
    __syncthreads();
    {
      float osc[4];
#pragma unroll
      for (int r = 0; r < 4; ++r) osc[r] = osc_st[lg * 4 + r];
#pragma unroll
      for (int ct = 0; ct < 4; ++ct)
#pragma unroll
        for (int r = 0; r < 4; ++r) oacc[ct][r] *= osc[r];
#pragma unroll
      for (int kc = 0; kc < 4; ++kc) {
        int lin = lr * 256 + (kc * 32 + 8 * lg) * 2;
        short8 pf = *(const short8*)((const char*)p_lds + (lin ^ ((lr & 7) << 4)));
        const float* vp0 = v + (size_t)(kb + kc * 32 + 8 * lg) * DIM + w * 64 + lr;
#pragma unroll
        for (int ct = 0; ct < 4; ++ct) {
          const float* vp = vp0 + ct * 16;
          short8 vf;
#pragma unroll
          for (int jj = 0; jj < 8; ++jj) vf[jj] = f2bf(vp[(size_t)jj * DIM]);
          oacc[ct] = __builtin_amdgcn_mfma_f32_16x16x32_bf16(pf, vf, oacc[ct], 0, 0, 0);
        }
      }
    }
    __syncthreads();
  }
  {
    float linv[4];
#pragma unroll
    for (int r = 0; r < 4; ++r) linv[r] = 1.f / l_st[lg * 4 + r];
#pragma unroll
    for (int ct = 0; ct < 4; ++ct)
#pragma unroll
      for (int r = 0; r < 4; ++r)
        out[(size_t)(qb + lg * 4 + r) * DIM + w * 64 + ct * 16 + lr] =
            oacc[ct][r] * linv[r];
  }
}

extern "C" void kernel_launch(void* const* d_in, const int* in_sizes, int n_in,
                              void* d_out, int out_size, void* d_ws, size_t ws_size,
                              hipStream_t stream) {
  (void)in_sizes; (void)n_in; (void)out_size;
  const float* q = (const float*)d_in[0];
  const float* k = (const float*)d_in[1];
  const float* v = (const float*)d_in[2];
  float* out = (float*)d_out;

  const size_t kbf_elems = (size_t)SEQ * DIM;
  const size_t vt_elems  = (size_t)DIM * SEQ;
  const size_t op_elems  = (size_t)SPLITS * SEQ * DIM;
  const size_t ml_elems  = (size_t)SPLITS * SEQ * 2;
  const size_t need = kbf_elems * 2 + vt_elems * 2 + op_elems * 4 + ml_elems * 4;

  if (ws_size >= need) {
    ushort* kbf  = (ushort*)d_ws;
    ushort* vtb  = kbf + kbf_elems;
    float* opart = (float*)(vtb + vt_elems);
    float* ml    = opart + op_elems;

    cvt_bf16<<<(SEQ * DIM / 8 + 255) / 256, 256, 0, stream>>>(k, kbf, SEQ * DIM / 8);
    transpose_bf16<<<(SEQ / 64) * (DIM / 64), 256, 0, stream>>>(v, vtb);
    attn_split<<<(SEQ / BQ) * SPLITS, 512, 0, stream>>>(q, kbf, vtb, opart, ml);
    combine<<<(SEQ * DIM / 4) / 256, 256, 0, stream>>>(opart, ml, out);
  } else {
    attn_fused_fb<<<SEQ / 16, 512, 0, stream>>>(q, k, v, out);
  }
}

// Round 14
// 79.701 us; speedup vs baseline: 1.5016x; 1.0921x over previous
//
#include <hip/hip_runtime.h>
#include <hip/hip_bf16.h>

#define SEQ 4096
#define DIM 512
#define SCALE 0.044194173824159216f  // 1/sqrt(512)

#define SPLITS 4
#define BQ 64
#define KVBLK 64
#define KEYS_PER_SPLIT (SEQ / SPLITS)    // 1024
#define ITERS (KEYS_PER_SPLIT / KVBLK)   // 16
#define THR_DEFER 8.0f

typedef __attribute__((ext_vector_type(8))) short short8;
typedef __attribute__((ext_vector_type(4))) float f32x4;
typedef __attribute__((ext_vector_type(16))) float f32x16;

__device__ __forceinline__ short f2bf(float f) {
  union { float f; unsigned u; } c; c.f = f;
  unsigned u = c.u;
  return (short)((u + 0x7FFFu + ((u >> 16) & 1u)) >> 16);
}

__device__ __forceinline__ float bf2f(unsigned short b) {
  union { unsigned u; float f; } c;
  c.u = ((unsigned)b) << 16;
  return c.f;
}

__device__ __forceinline__ short8 pack8(float4 a, float4 b) {
  short8 r;
  r[0] = f2bf(a.x); r[1] = f2bf(a.y); r[2] = f2bf(a.z); r[3] = f2bf(a.w);
  r[4] = f2bf(b.x); r[5] = f2bf(b.y); r[6] = f2bf(b.z); r[7] = f2bf(b.w);
  return r;
}

__device__ __forceinline__ ushort4 pack4(float a, float b, float c, float d) {
  ushort4 r;
  r.x = (unsigned short)f2bf(a); r.y = (unsigned short)f2bf(b);
  r.z = (unsigned short)f2bf(c); r.w = (unsigned short)f2bf(d);
  return r;
}

// async global->LDS, 16B per lane, dest = uniform base + lane*16
__device__ __forceinline__ void gload16(const void* g, void* l) {
  __builtin_amdgcn_global_load_lds(
      (const __attribute__((address_space(1))) unsigned int*)g,
      (__attribute__((address_space(3))) unsigned int*)l, 16, 0, 0);
}

// ---------- fused prep: blocks [0,1024): K fp32->bf16; [1024,1536): V -> V^T bf16 ----------
__global__ void prep_fused(const float* __restrict__ k, ushort* __restrict__ kbf,
                           const float* __restrict__ v, ushort* __restrict__ vt) {
  __shared__ float t[64][65];
  const int tid = threadIdx.x;
  if (blockIdx.x < 1024) {
    int i = blockIdx.x * 256 + tid;  // 8 elems each, 1024*256*8 = SEQ*DIM
    const float4* p = (const float4*)(k + (size_t)i * 8);
    short8 o = pack8(p[0], p[1]);
    *(short8*)(kbf + (size_t)i * 8) = o;
    return;
  }
  const int bid = blockIdx.x - 1024;
  const int bs = bid % (SEQ / 64);
  const int bd = bid / (SEQ / 64);
  const int s0 = bs * 64, d0 = bd * 64;
#pragma unroll
  for (int kk = 0; kk < 16; ++kk) {
    int idx = kk * 256 + tid;
    int r = idx >> 6, c = idx & 63;
    t[r][c] = v[(size_t)(s0 + r) * DIM + d0 + c];
  }
  __syncthreads();
#pragma unroll
  for (int kk = 0; kk < 16; ++kk) {
    int idx = kk * 256 + tid;
    int dr = idx >> 6, sc = idx & 63;
    vt[(size_t)(d0 + dr) * SEQ + s0 + sc] = (ushort)f2bf(t[sc][dr]);
  }
}

// ---------- fused attention (round-13 structure; opart in bf16) ----------
// QK role:  rg = w&3 (16 q-rows), kh = w>>2 (32-key half). Swapped QK^T
//           (mfma(K,Q) -> S^T) => in-register softmax; cross-kh max merge
//           via mx_st LDS exchange (folded into bar-B).
// PV role:  rg_pv = w&1 (32 q-rows), cg = w>>1 (128 out cols), 32x32x16 MFMA.
// Per iter: vmcnt(0) -> BAR-A -> stageV(t) -> QK(t) -> lgkm -> BAR-B
//           -> stageK(t+1) -> SM(t) -> vmcnt(8) lgkm -> BAR-C -> PV(t)
__global__ __launch_bounds__(512, 2) void attn_split(
    const float* __restrict__ q, const ushort* __restrict__ kbf,
    const ushort* __restrict__ vt, ushort* __restrict__ opart,
    float* __restrict__ ml) {
  __shared__ __align__(16) ushort kt[KVBLK * DIM];    // 64 KB, granule16 ^= row&31
  __shared__ __align__(16) ushort vtt[DIM * KVBLK];   // 64 KB, granule16 ^= row&7
  __shared__ __align__(16) ushort p_lds[BQ * KVBLK];  // 8 KB,  byte ^= (row&7)<<4
  __shared__ float mx_st[2][BQ];                      // per-kh tile max exchange
  __shared__ float osc_st[BQ];                        // per-row rescale factor
  __shared__ float l_st[2][BQ];                       // epilogue l merge
  __shared__ int   flag_st[4];                        // per 16-row strip: rescaled?

  const int tid  = threadIdx.x;
  const int lane = tid & 63;
  const int w    = tid >> 6;
  const int lr   = lane & 15;
  const int lg   = lane >> 4;
  const int l31  = lane & 31;
  const int hi   = lane >> 5;
  const int sp   = blockIdx.x & (SPLITS - 1);
  const int qb   = blockIdx.x >> 2;
  const int rg   = w & 3;    // QK row-group (16 rows)
  const int kh   = w >> 2;   // QK key-half (32 keys)
  const int rg_pv = w & 1;   // PV row-group (32 rows)
  const int cg    = w >> 1;  // PV col-group (128 cols)
  const int qrow0 = qb * BQ;
  const int kbase = sp * KEYS_PER_SPLIT;

  // Q fragments (B-operand 16x16x32): col=qrow=lr, k=lg*8+j
  short8 qf[16];
  {
    const float* qp = q + (size_t)(qrow0 + rg * 16 + lr) * DIM + lg * 8;
#pragma unroll
    for (int c = 0; c < 16; ++c)
      qf[c] = pack8(*(const float4*)(qp + c * 32), *(const float4*)(qp + c * 32 + 4));
  }
  f32x16 oacc[4] = {};
  float m_reg = -INFINITY, l_reg = 0.f;

  // K rows 1KB: LDS[r][g16] = K[kb+r][(g16 ^ (r&31))*8..]; 8 gloads/wave
  auto stageK = [&](int kb) {
#pragma unroll
    for (int i = 0; i < 8; ++i) {
      int r = w * 8 + i;
      const ushort* src = kbf + (size_t)(kb + r) * DIM + ((lane ^ (r & 31)) * 8);
      gload16(src, &kt[r * DIM]);
    }
  };
  // V^T rows 128B: LDS[d][g] = vt[d][kb + ((g^(d&7))*8)..]; 8 gloads/wave
  auto stageV = [&](int kb) {
#pragma unroll
    for (int j = 0; j < 8; ++j) {
      int r0 = w * 64 + j * 8;
      int rr = r0 + (lane >> 3);
      const ushort* src = vt + (size_t)rr * SEQ + kb + (((lane & 7) ^ (rr & 7)) * 8);
      gload16(src, &vtt[r0 * KVBLK]);
    }
  };

  stageK(kbase);  // K(0) in flight

#pragma unroll 1
  for (int it = 0; it < ITERS; ++it) {
    const int kb = kbase + it * KVBLK;

    asm volatile("s_waitcnt vmcnt(0)" ::: "memory");  // K(t) landed (only K in queue)
    __builtin_amdgcn_s_barrier();  // bar-A: kt(t) ready; all PV(t-1) vtt reads done

    stageV(kb);  // V(t) -> vtt, safe post-bar-A; lands during QK/SM

    // ---- swapped QK^T (16x16x32): S^T[key][qrow] for wave's 32 keys ----
    f32x4 s0 = {}, s1 = {};
    {
      const int kr0 = kh * 32 + lr;
      const int kr1 = kr0 + 16;
      const char* kb0 = (const char*)kt + kr0 * 1024;
      const char* kb1 = (const char*)kt + kr1 * 1024;
      const int sw0 = kr0 & 31, sw1 = kr1 & 31;
      __builtin_amdgcn_s_setprio(1);
#pragma unroll
      for (int c = 0; c < 16; ++c) {
        short8 k0 = *(const short8*)(kb0 + (((c * 4 + lg) ^ sw0) << 4));
        short8 k1 = *(const short8*)(kb1 + (((c * 4 + lg) ^ sw1) << 4));
        s0 = __builtin_amdgcn_mfma_f32_16x16x32_bf16(k0, qf[c], s0, 0, 0, 0);
        s1 = __builtin_amdgcn_mfma_f32_16x16x32_bf16(k1, qf[c], s1, 0, 0, 0);
      }
      __builtin_amdgcn_s_setprio(0);
    }

    // per-row tile max over wave's 32 keys (lane owns qrow=lr)
    float sc0[4], sc1[4];
#pragma unroll
    for (int r = 0; r < 4; ++r) { sc0[r] = s0[r] * SCALE; sc1[r] = s1[r] * SCALE; }
    float tmax = fmaxf(fmaxf(fmaxf(sc0[0], sc0[1]), fmaxf(sc0[2], sc0[3])),
                       fmaxf(fmaxf(sc1[0], sc1[1]), fmaxf(sc1[2], sc1[3])));
    tmax = fmaxf(tmax, __shfl_xor(tmax, 16));
    tmax = fmaxf(tmax, __shfl_xor(tmax, 32));
    if (lane < 16) mx_st[kh][rg * 16 + lane] = tmax;

    asm volatile("s_waitcnt lgkmcnt(0)" ::: "memory");
    __builtin_amdgcn_s_barrier();                     // bar-B: kt consumed, mx visible

    if (it + 1 < ITERS) stageK(kb + KVBLK);  // K(t+1) lands during PV

    // ---- softmax finish: common m across kh pair, defer-max, P -> LDS ----
    {
      const int row = rg * 16 + lr;
      float tmax64 = fmaxf(mx_st[0][row], mx_st[1][row]);
      bool resc = tmax64 > m_reg + THR_DEFER;
      float mnew = resc ? tmax64 : m_reg;
      float osc = __expf(m_reg - mnew);  // 1.0 when deferred; 0 on first tile
      unsigned long long bl = __ballot(resc);
      if (kh == 0 && lane == 0) flag_st[rg] = (bl != 0ull) ? 1 : 0;
      if (kh == 0 && lane < 16) osc_st[row] = osc;
      m_reg = mnew;
      l_reg *= osc;
      float p0[4], p1[4];
#pragma unroll
      for (int r = 0; r < 4; ++r) {
        p0[r] = __expf(sc0[r] - m_reg);
        p1[r] = __expf(sc1[r] - m_reg);
      }
      float ps = ((p0[0] + p0[1]) + (p0[2] + p0[3])) +
                 ((p1[0] + p1[1]) + (p1[2] + p1[3]));
      ps += __shfl_xor(ps, 16);
      ps += __shfl_xor(ps, 32);
      l_reg += ps;
      // P write: row=qrow, keys kh*32+lg*4+r (+16 for s1); swizzle (row&7)<<4
      char* pb = (char*)p_lds + row * 128;
      const int sw = (row & 7) << 4;
      const int off = kh * 64 + lg * 8;
      *(ushort4*)(pb + (off ^ sw))        = pack4(p0[0], p0[1], p0[2], p0[3]);
      *(ushort4*)(pb + ((off + 32) ^ sw)) = pack4(p1[0], p1[1], p1[2], p1[3]);
    }

    if (it + 1 < ITERS) {
      asm volatile("s_waitcnt vmcnt(8)" ::: "memory");  // V(t) landed (K(t+1)=8 out)
    } else {
      asm volatile("s_waitcnt vmcnt(0)" ::: "memory");  // drain V(t)
    }
    asm volatile("s_waitcnt lgkmcnt(0)" ::: "memory");  // p_lds/osc/flag visible
    __builtin_amdgcn_s_barrier();                       // bar-C

    // ---- PV (32x32x16): rows rg_pv*32.., cols cg*128.. ----
    {
      if (flag_st[rg_pv * 2] | flag_st[rg_pv * 2 + 1]) {
        float ov[16];
#pragma unroll
        for (int r = 0; r < 16; ++r)
          ov[r] = osc_st[rg_pv * 32 + (r & 3) + 8 * (r >> 2) + 4 * hi];
#pragma unroll
        for (int t = 0; t < 4; ++t)
#pragma unroll
          for (int r = 0; r < 16; ++r) oacc[t][r] *= ov[r];
      }
      const int arow = rg_pv * 32 + l31;
      const char* prow = (const char*)p_lds + arow * 128;
      const int psw = (arow & 7) << 4;
      __builtin_amdgcn_s_setprio(1);
#pragma unroll
      for (int c = 0; c < 4; ++c) {
        short8 pa = *(const short8*)(prow + ((c * 32 + hi * 16) ^ psw));
#pragma unroll
        for (int t = 0; t < 4; ++t) {
          int vrow = cg * 128 + t * 32 + l31;
          short8 vf = *(const short8*)((const char*)vtt + vrow * 128 +
                                       ((c * 32 + hi * 16) ^ ((vrow & 7) << 4)));
          oacc[t] = __builtin_amdgcn_mfma_f32_32x32x16_bf16(pa, vf, oacc[t], 0, 0, 0);
        }
      }
      __builtin_amdgcn_s_setprio(0);
    }
    // no bar-D: bar-A of next iter covers vtt reuse
  }

  // ---- epilogue: merge l across kh, write opart (bf16) + ml ----
  if (lane < 16) {
    l_st[kh][rg * 16 + lane] = l_reg;
    if (kh == 0) mx_st[0][rg * 16 + lane] = m_reg;
  }
  __syncthreads();
  {
    ushort* op = opart + ((size_t)sp * SEQ + qrow0 + rg_pv * 32) * DIM + cg * 128;
#pragma unroll
    for (int t = 0; t < 4; ++t)
#pragma unroll
      for (int r = 0; r < 16; ++r) {
        int crow = (r & 3) + 8 * (r >> 2) + 4 * hi;
        op[(size_t)crow * DIM + t * 32 + l31] = (ushort)f2bf(oacc[t][r]);
      }
  }
  if (tid < BQ) {
    size_t base = ((size_t)sp * SEQ + qrow0 + tid) * 2;
    ml[base]     = mx_st[0][tid];
    ml[base + 1] = l_st[0][tid] + l_st[1][tid];
  }
}

// ---------- combine split partials (bf16 opart, 8 elems/thread) ----------
__global__ void combine(const ushort* __restrict__ opart, const float* __restrict__ ml,
                        float* __restrict__ out) {
  int gid = blockIdx.x * 256 + threadIdx.x;
  int row = gid >> 6;          // DIM/8 = 64 chunks per row
  int dv  = (gid & 63) * 8;
  float m[SPLITS], l[SPLITS], wgt[SPLITS];
  float M = -INFINITY;
#pragma unroll
  for (int i = 0; i < SPLITS; ++i) {
    m[i] = ml[((size_t)i * SEQ + row) * 2];
    l[i] = ml[((size_t)i * SEQ + row) * 2 + 1];
    M = fmaxf(M, m[i]);
  }
  float L = 0.f;
#pragma unroll
  for (int i = 0; i < SPLITS; ++i) { wgt[i] = __expf(m[i] - M); L += l[i] * wgt[i]; }
  float inv = 1.f / L;
  float acc[8] = {};
#pragma unroll
  for (int i = 0; i < SPLITS; ++i) {
    short8 o = *(const short8*)(opart + ((size_t)i * SEQ + row) * DIM + dv);
#pragma unroll
    for (int j = 0; j < 8; ++j) acc[j] += bf2f((unsigned short)o[j]) * wgt[i];
  }
  float4 r0, r1;
  r0.x = acc[0] * inv; r0.y = acc[1] * inv; r0.z = acc[2] * inv; r0.w = acc[3] * inv;
  r1.x = acc[4] * inv; r1.y = acc[5] * inv; r1.z = acc[6] * inv; r1.w = acc[7] * inv;
  *(float4*)(out + (size_t)row * DIM + dv)     = r0;
  *(float4*)(out + (size_t)row * DIM + dv + 4) = r1;
}

// ---------- fallback if ws too small ----------
__global__ __launch_bounds__(512) void attn_fused_fb(
    const float* __restrict__ q, const float* __restrict__ k,
    const float* __restrict__ v, float* __restrict__ out) {
  __shared__ float s_lds[16][128];
  __shared__ __align__(16) unsigned short p_lds[16 * 128];
  __shared__ float m_st[16], l_st[16], osc_st[16];
  const int tid = threadIdx.x, lane = tid & 63, w = tid >> 6;
  const int lr = lane & 15, lg = lane >> 4, qb = blockIdx.x * 16;
  if (tid < 16) { m_st[tid] = -INFINITY; l_st[tid] = 0.f; }
  short8 qf[16];
  {
    const float* qp = q + (size_t)(qb + lr) * DIM + lg * 8;
#pragma unroll
    for (int c = 0; c < 16; ++c)
      qf[c] = pack8(*(const float4*)(qp + c * 32), *(const float4*)(qp + c * 32 + 4));
  }
  f32x4 oacc[4] = {};
  __syncthreads();
  for (int it = 0; it < SEQ / 128; ++it) {
    const int kb = it * 128;
    {
      const float* kp = k + (size_t)(kb + w * 16 + lr) * DIM + lg * 8;
      f32x4 sacc = {};
#pragma unroll
      for (int c = 0; c < 16; ++c) {
        short8 kf = pack8(*(const float4*)(kp + c * 32), *(const float4*)(kp + c * 32 + 4));
        sacc = __builtin_amdgcn_mfma_f32_16x16x32_bf16(qf[c], kf, sacc, 0, 0, 0);
      }
#pragma unroll
      for (int r = 0; r < 4; ++r) s_lds[lg * 4 + r][w * 16 + lr] = sacc[r] * SCALE;
    }
    __syncthreads();
    {
      const int srow = tid >> 5, sj = tid & 31;
      float4 sv = *(const float4*)&s_lds[srow][sj * 4];
      float tmax = fmaxf(fmaxf(sv.x, sv.y), fmaxf(sv.z, sv.w));
#pragma unroll
      for (int m = 16; m >= 1; m >>= 1) tmax = fmaxf(tmax, __shfl_xor(tmax, m));
      float mold = m_st[srow], mnew = fmaxf(mold, tmax);
      float p0 = __expf(sv.x - mnew), p1 = __expf(sv.y - mnew);
      float p2 = __expf(sv.z - mnew), p3 = __expf(sv.w - mnew);
      float psum = (p0 + p1) + (p2 + p3);
#pragma unroll
      for (int m = 16; m >= 1; m >>= 1) psum += __shfl_xor(psum, m);
      if (sj == 0) {
        float sc = __expf(mold - mnew);
        l_st[srow] = l_st[srow] * sc + psum; m_st[srow] = mnew; osc_st[srow] = sc;
      }
      ushort4 pb;
      pb.x = (unsigned short)f2bf(p0); pb.y = (unsigned short)f2bf(p1);
      pb.z = (unsigned short)f2bf(p2); pb.w = (unsigned short)f2bf(p3);
      int lin = srow * 256 + sj * 8;
      *(ushort4*)((char*)p_lds + (lin ^ ((srow & 7) << 4))) = pb;
    }
    __syncthreads();
    {
      float osc[4];
#pragma unroll
      for (int r = 0; r < 4; ++r) osc[r] = osc_st[lg * 4 + r];
#pragma unroll
      for (int ct = 0; ct < 4; ++ct)
#pragma unroll
        for (int r = 0; r < 4; ++r) oacc[ct][r] *= osc[r];
#pragma unroll
      for (int kc = 0; kc < 4; ++kc) {
        int lin = lr * 256 + (kc * 32 + 8 * lg) * 2;
        short8 pf = *(const short8*)((const char*)p_lds + (lin ^ ((lr & 7) << 4)));
        const float* vp0 = v + (size_t)(kb + kc * 32 + 8 * lg) * DIM + w * 64 + lr;
#pragma unroll
        for (int ct = 0; ct < 4; ++ct) {
          const float* vp = vp0 + ct * 16;
          short8 vf;
#pragma unroll
          for (int jj = 0; jj < 8; ++jj) vf[jj] = f2bf(vp[(size_t)jj * DIM]);
          oacc[ct] = __builtin_amdgcn_mfma_f32_16x16x32_bf16(pf, vf, oacc[ct], 0, 0, 0);
        }
      }
    }
    __syncthreads();
  }
  {
    float linv[4];
#pragma unroll
    for (int r = 0; r < 4; ++r) linv[r] = 1.f / l_st[lg * 4 + r];
#pragma unroll
    for (int ct = 0; ct < 4; ++ct)
#pragma unroll
      for (int r = 0; r < 4; ++r)
        out[(size_t)(qb + lg * 4 + r) * DIM + w * 64 + ct * 16 + lr] =
            oacc[ct][r] * linv[r];
  }
}

extern "C" void kernel_launch(void* const* d_in, const int* in_sizes, int n_in,
                              void* d_out, int out_size, void* d_ws, size_t ws_size,
                              hipStream_t stream) {
  (void)in_sizes; (void)n_in; (void)out_size;
  const float* q = (const float*)d_in[0];
  const float* k = (const float*)d_in[1];
  const float* v = (const float*)d_in[2];
  float* out = (float*)d_out;

  const size_t kbf_elems = (size_t)SEQ * DIM;
  const size_t vt_elems  = (size_t)DIM * SEQ;
  const size_t op_elems  = (size_t)SPLITS * SEQ * DIM;   // bf16 now
  const size_t ml_elems  = (size_t)SPLITS * SEQ * 2;
  const size_t need = kbf_elems * 2 + vt_elems * 2 + op_elems * 2 + ml_elems * 4;

  if (ws_size >= need) {
    ushort* kbf  = (ushort*)d_ws;
    ushort* vtb  = kbf + kbf_elems;
    ushort* opart = vtb + vt_elems;
    float* ml    = (float*)(opart + op_elems);

    prep_fused<<<1024 + (SEQ / 64) * (DIM / 64), 256, 0, stream>>>(k, kbf, v, vtb);
    attn_split<<<(SEQ / BQ) * SPLITS, 512, 0, stream>>>(q, kbf, vtb, opart, ml);
    combine<<<(SEQ * DIM / 8) / 256, 256, 0, stream>>>(opart, ml, out);
  } else {
    attn_fused_fb<<<SEQ / 16, 512, 0, stream>>>(q, k, v, out);
  }
}

// Round 15
// 75.075 us; speedup vs baseline: 1.5941x; 1.0616x over previous
//
#include <hip/hip_runtime.h>
#include <hip/hip_bf16.h>

#define SEQ 4096
#define DIM 512
#define SCALE 0.044194173824159216f  // 1/sqrt(512)

#define SPLITS 4
#define BQ 64
#define KVBLK 64
#define KEYS_PER_SPLIT (SEQ / SPLITS)    // 1024
#define ITERS (KEYS_PER_SPLIT / KVBLK)   // 16
#define THR_DEFER 8.0f

typedef __attribute__((ext_vector_type(8))) short short8;
typedef __attribute__((ext_vector_type(4))) float f32x4;
typedef __attribute__((ext_vector_type(16))) float f32x16;

__device__ __forceinline__ short f2bf(float f) {
  union { float f; unsigned u; } c; c.f = f;
  unsigned u = c.u;
  return (short)((u + 0x7FFFu + ((u >> 16) & 1u)) >> 16);
}

__device__ __forceinline__ float bf2f(unsigned short b) {
  union { unsigned u; float f; } c;
  c.u = ((unsigned)b) << 16;
  return c.f;
}

__device__ __forceinline__ short8 pack8(float4 a, float4 b) {
  short8 r;
  r[0] = f2bf(a.x); r[1] = f2bf(a.y); r[2] = f2bf(a.z); r[3] = f2bf(a.w);
  r[4] = f2bf(b.x); r[5] = f2bf(b.y); r[6] = f2bf(b.z); r[7] = f2bf(b.w);
  return r;
}

__device__ __forceinline__ ushort4 pack4(float a, float b, float c, float d) {
  ushort4 r;
  r.x = (unsigned short)f2bf(a); r.y = (unsigned short)f2bf(b);
  r.z = (unsigned short)f2bf(c); r.w = (unsigned short)f2bf(d);
  return r;
}

// async global->LDS, 16B per lane, dest = uniform base + lane*16
__device__ __forceinline__ void gload16(const void* g, void* l) {
  __builtin_amdgcn_global_load_lds(
      (const __attribute__((address_space(1))) unsigned int*)g,
      (__attribute__((address_space(3))) unsigned int*)l, 16, 0, 0);
}

// ---------- fused prep ----------
// blocks [0,1024):    K fp32 -> bf16 row-major
// blocks [1024,2048): Q fp32 -> bf16 row-major (identical rounding to in-kernel pack8)
// blocks [2048,2560): V fp32 (SxD) -> bf16 V^T (DxS)
__global__ void prep_fused(const float* __restrict__ k, ushort* __restrict__ kbf,
                           const float* __restrict__ q, ushort* __restrict__ qbf,
                           const float* __restrict__ v, ushort* __restrict__ vt) {
  __shared__ float t[64][65];
  const int tid = threadIdx.x;
  if (blockIdx.x < 1024) {
    int i = blockIdx.x * 256 + tid;  // 8 elems each
    const float4* p = (const float4*)(k + (size_t)i * 8);
    *(short8*)(kbf + (size_t)i * 8) = pack8(p[0], p[1]);
    return;
  }
  if (blockIdx.x < 2048) {
    int i = (blockIdx.x - 1024) * 256 + tid;
    const float4* p = (const float4*)(q + (size_t)i * 8);
    *(short8*)(qbf + (size_t)i * 8) = pack8(p[0], p[1]);
    return;
  }
  const int bid = blockIdx.x - 2048;
  const int bs = bid % (SEQ / 64);
  const int bd = bid / (SEQ / 64);
  const int s0 = bs * 64, d0 = bd * 64;
#pragma unroll
  for (int kk = 0; kk < 16; ++kk) {
    int idx = kk * 256 + tid;
    int r = idx >> 6, c = idx & 63;
    t[r][c] = v[(size_t)(s0 + r) * DIM + d0 + c];
  }
  __syncthreads();
#pragma unroll
  for (int kk = 0; kk < 16; ++kk) {
    int idx = kk * 256 + tid;
    int dr = idx >> 6, sc = idx & 63;
    vt[(size_t)(d0 + dr) * SEQ + s0 + sc] = (ushort)f2bf(t[sc][dr]);
  }
}

// ---------- fused attention (round-14 structure; Q pre-converted bf16) ----------
// QK role:  rg = w&3 (16 q-rows), kh = w>>2 (32-key half). Swapped QK^T
//           (mfma(K,Q) -> S^T) => in-register softmax; cross-kh max merge
//           via mx_st LDS exchange (folded into bar-B).
// PV role:  rg_pv = w&1 (32 q-rows), cg = w>>1 (128 out cols), 32x32x16 MFMA.
// Per iter: vmcnt(0) -> BAR-A -> stageV(t) -> QK(t) -> lgkm -> BAR-B
//           -> stageK(t+1) -> SM(t) -> vmcnt(8) lgkm -> BAR-C -> PV(t)
__global__ __launch_bounds__(512, 2) void attn_split(
    const ushort* __restrict__ qbf, const ushort* __restrict__ kbf,
    const ushort* __restrict__ vt, ushort* __restrict__ opart,
    float* __restrict__ ml) {
  __shared__ __align__(16) ushort kt[KVBLK * DIM];    // 64 KB, granule16 ^= row&31
  __shared__ __align__(16) ushort vtt[DIM * KVBLK];   // 64 KB, granule16 ^= row&7
  __shared__ __align__(16) ushort p_lds[BQ * KVBLK];  // 8 KB,  byte ^= (row&7)<<4
  __shared__ float mx_st[2][BQ];                      // per-kh tile max exchange
  __shared__ float osc_st[BQ];                        // per-row rescale factor
  __shared__ float l_st[2][BQ];                       // epilogue l merge
  __shared__ int   flag_st[4];                        // per 16-row strip: rescaled?

  const int tid  = threadIdx.x;
  const int lane = tid & 63;
  const int w    = tid >> 6;
  const int lr   = lane & 15;
  const int lg   = lane >> 4;
  const int l31  = lane & 31;
  const int hi   = lane >> 5;
  const int sp   = blockIdx.x & (SPLITS - 1);
  const int qb   = blockIdx.x >> 2;
  const int rg   = w & 3;    // QK row-group (16 rows)
  const int kh   = w >> 2;   // QK key-half (32 keys)
  const int rg_pv = w & 1;   // PV row-group (32 rows)
  const int cg    = w >> 1;  // PV col-group (128 cols)
  const int qrow0 = qb * BQ;
  const int kbase = sp * KEYS_PER_SPLIT;

  // Q fragments (B-operand 16x16x32): col=qrow=lr, k=lg*8+j  (pre-converted bf16)
  short8 qf[16];
  {
    const ushort* qp = qbf + (size_t)(qrow0 + rg * 16 + lr) * DIM + lg * 8;
#pragma unroll
    for (int c = 0; c < 16; ++c)
      qf[c] = *(const short8*)(qp + c * 32);
  }
  f32x16 oacc[4] = {};
  float m_reg = -INFINITY, l_reg = 0.f;

  // K rows 1KB: LDS[r][g16] = K[kb+r][(g16 ^ (r&31))*8..]; 8 gloads/wave
  auto stageK = [&](int kb) {
#pragma unroll
    for (int i = 0; i < 8; ++i) {
      int r = w * 8 + i;
      const ushort* src = kbf + (size_t)(kb + r) * DIM + ((lane ^ (r & 31)) * 8);
      gload16(src, &kt[r * DIM]);
    }
  };
  // V^T rows 128B: LDS[d][g] = vt[d][kb + ((g^(d&7))*8)..]; 8 gloads/wave
  auto stageV = [&](int kb) {
#pragma unroll
    for (int j = 0; j < 8; ++j) {
      int r0 = w * 64 + j * 8;
      int rr = r0 + (lane >> 3);
      const ushort* src = vt + (size_t)rr * SEQ + kb + (((lane & 7) ^ (rr & 7)) * 8);
      gload16(src, &vtt[r0 * KVBLK]);
    }
  };

  stageK(kbase);  // K(0) in flight

#pragma unroll 1
  for (int it = 0; it < ITERS; ++it) {
    const int kb = kbase + it * KVBLK;

    asm volatile("s_waitcnt vmcnt(0)" ::: "memory");  // K(t) landed (only K in queue)
    __builtin_amdgcn_s_barrier();  // bar-A: kt(t) ready; all PV(t-1) vtt reads done

    stageV(kb);  // V(t) -> vtt, safe post-bar-A; lands during QK/SM

    // ---- swapped QK^T (16x16x32): S^T[key][qrow] for wave's 32 keys ----
    f32x4 s0 = {}, s1 = {};
    {
      const int kr0 = kh * 32 + lr;
      const int kr1 = kr0 + 16;
      const char* kb0 = (const char*)kt + kr0 * 1024;
      const char* kb1 = (const char*)kt + kr1 * 1024;
      const int sw0 = kr0 & 31, sw1 = kr1 & 31;
      __builtin_amdgcn_s_setprio(1);
#pragma unroll
      for (int c = 0; c < 16; ++c) {
        short8 k0 = *(const short8*)(kb0 + (((c * 4 + lg) ^ sw0) << 4));
        short8 k1 = *(const short8*)(kb1 + (((c * 4 + lg) ^ sw1) << 4));
        s0 = __builtin_amdgcn_mfma_f32_16x16x32_bf16(k0, qf[c], s0, 0, 0, 0);
        s1 = __builtin_amdgcn_mfma_f32_16x16x32_bf16(k1, qf[c], s1, 0, 0, 0);
      }
      __builtin_amdgcn_s_setprio(0);
    }

    // per-row tile max over wave's 32 keys (lane owns qrow=lr)
    float sc0[4], sc1[4];
#pragma unroll
    for (int r = 0; r < 4; ++r) { sc0[r] = s0[r] * SCALE; sc1[r] = s1[r] * SCALE; }
    float tmax = fmaxf(fmaxf(fmaxf(sc0[0], sc0[1]), fmaxf(sc0[2], sc0[3])),
                       fmaxf(fmaxf(sc1[0], sc1[1]), fmaxf(sc1[2], sc1[3])));
    tmax = fmaxf(tmax, __shfl_xor(tmax, 16));
    tmax = fmaxf(tmax, __shfl_xor(tmax, 32));
    if (lane < 16) mx_st[kh][rg * 16 + lane] = tmax;

    asm volatile("s_waitcnt lgkmcnt(0)" ::: "memory");
    __builtin_amdgcn_s_barrier();                     // bar-B: kt consumed, mx visible

    if (it + 1 < ITERS) stageK(kb + KVBLK);  // K(t+1) lands during PV

    // ---- softmax finish: common m across kh pair, defer-max, P -> LDS ----
    {
      const int row = rg * 16 + lr;
      float tmax64 = fmaxf(mx_st[0][row], mx_st[1][row]);
      bool resc = tmax64 > m_reg + THR_DEFER;
      float mnew = resc ? tmax64 : m_reg;
      float osc = __expf(m_reg - mnew);  // 1.0 when deferred; 0 on first tile
      unsigned long long bl = __ballot(resc);
      if (kh == 0 && lane == 0) flag_st[rg] = (bl != 0ull) ? 1 : 0;
      if (kh == 0 && lane < 16) osc_st[row] = osc;
      m_reg = mnew;
      l_reg *= osc;
      float p0[4], p1[4];
#pragma unroll
      for (int r = 0; r < 4; ++r) {
        p0[r] = __expf(sc0[r] - m_reg);
        p1[r] = __expf(sc1[r] - m_reg);
      }
      float ps = ((p0[0] + p0[1]) + (p0[2] + p0[3])) +
                 ((p1[0] + p1[1]) + (p1[2] + p1[3]));
      ps += __shfl_xor(ps, 16);
      ps += __shfl_xor(ps, 32);
      l_reg += ps;
      // P write: row=qrow, keys kh*32+lg*4+r (+16 for s1); swizzle (row&7)<<4
      char* pb = (char*)p_lds + row * 128;
      const int sw = (row & 7) << 4;
      const int off = kh * 64 + lg * 8;
      *(ushort4*)(pb + (off ^ sw))        = pack4(p0[0], p0[1], p0[2], p0[3]);
      *(ushort4*)(pb + ((off + 32) ^ sw)) = pack4(p1[0], p1[1], p1[2], p1[3]);
    }

    if (it + 1 < ITERS) {
      asm volatile("s_waitcnt vmcnt(8)" ::: "memory");  // V(t) landed (K(t+1)=8 out)
    } else {
      asm volatile("s_waitcnt vmcnt(0)" ::: "memory");  // drain V(t)
    }
    asm volatile("s_waitcnt lgkmcnt(0)" ::: "memory");  // p_lds/osc/flag visible
    __builtin_amdgcn_s_barrier();                       // bar-C

    // ---- PV (32x32x16): rows rg_pv*32.., cols cg*128.. ----
    {
      if (flag_st[rg_pv * 2] | flag_st[rg_pv * 2 + 1]) {
        float ov[16];
#pragma unroll
        for (int r = 0; r < 16; ++r)
          ov[r] = osc_st[rg_pv * 32 + (r & 3) + 8 * (r >> 2) + 4 * hi];
#pragma unroll
        for (int t = 0; t < 4; ++t)
#pragma unroll
          for (int r = 0; r < 16; ++r) oacc[t][r] *= ov[r];
      }
      const int arow = rg_pv * 32 + l31;
      const char* prow = (const char*)p_lds + arow * 128;
      const int psw = (arow & 7) << 4;
      __builtin_amdgcn_s_setprio(1);
#pragma unroll
      for (int c = 0; c < 4; ++c) {
        short8 pa = *(const short8*)(prow + ((c * 32 + hi * 16) ^ psw));
#pragma unroll
        for (int t = 0; t < 4; ++t) {
          int vrow = cg * 128 + t * 32 + l31;
          short8 vf = *(const short8*)((const char*)vtt + vrow * 128 +
                                       ((c * 32 + hi * 16) ^ ((vrow & 7) << 4)));
          oacc[t] = __builtin_amdgcn_mfma_f32_32x32x16_bf16(pa, vf, oacc[t], 0, 0, 0);
        }
      }
      __builtin_amdgcn_s_setprio(0);
    }
    // no bar-D: bar-A of next iter covers vtt reuse
  }

  // ---- epilogue: merge l across kh, write opart (bf16) + ml ----
  if (lane < 16) {
    l_st[kh][rg * 16 + lane] = l_reg;
    if (kh == 0) mx_st[0][rg * 16 + lane] = m_reg;
  }
  __syncthreads();
  {
    ushort* op = opart + ((size_t)sp * SEQ + qrow0 + rg_pv * 32) * DIM + cg * 128;
#pragma unroll
    for (int t = 0; t < 4; ++t)
#pragma unroll
      for (int r = 0; r < 16; ++r) {
        int crow = (r & 3) + 8 * (r >> 2) + 4 * hi;
        op[(size_t)crow * DIM + t * 32 + l31] = (ushort)f2bf(oacc[t][r]);
      }
  }
  if (tid < BQ) {
    size_t base = ((size_t)sp * SEQ + qrow0 + tid) * 2;
    ml[base]     = mx_st[0][tid];
    ml[base + 1] = l_st[0][tid] + l_st[1][tid];
  }
}

// ---------- combine split partials (bf16 opart, 8 elems/thread) ----------
__global__ void combine(const ushort* __restrict__ opart, const float* __restrict__ ml,
                        float* __restrict__ out) {
  int gid = blockIdx.x * 256 + threadIdx.x;
  int row = gid >> 6;          // DIM/8 = 64 chunks per row
  int dv  = (gid & 63) * 8;
  float m[SPLITS], l[SPLITS], wgt[SPLITS];
  float M = -INFINITY;
#pragma unroll
  for (int i = 0; i < SPLITS; ++i) {
    m[i] = ml[((size_t)i * SEQ + row) * 2];
    l[i] = ml[((size_t)i * SEQ + row) * 2 + 1];
    M = fmaxf(M, m[i]);
  }
  float L = 0.f;
#pragma unroll
  for (int i = 0; i < SPLITS; ++i) { wgt[i] = __expf(m[i] - M); L += l[i] * wgt[i]; }
  float inv = 1.f / L;
  float acc[8] = {};
#pragma unroll
  for (int i = 0; i < SPLITS; ++i) {
    short8 o = *(const short8*)(opart + ((size_t)i * SEQ + row) * DIM + dv);
#pragma unroll
    for (int j = 0; j < 8; ++j) acc[j] += bf2f((unsigned short)o[j]) * wgt[i];
  }
  float4 r0, r1;
  r0.x = acc[0] * inv; r0.y = acc[1] * inv; r0.z = acc[2] * inv; r0.w = acc[3] * inv;
  r1.x = acc[4] * inv; r1.y = acc[5] * inv; r1.z = acc[6] * inv; r1.w = acc[7] * inv;
  *(float4*)(out + (size_t)row * DIM + dv)     = r0;
  *(float4*)(out + (size_t)row * DIM + dv + 4) = r1;
}

// ---------- fallback if ws too small ----------
__global__ __launch_bounds__(512) void attn_fused_fb(
    const float* __restrict__ q, const float* __restrict__ k,
    const float* __restrict__ v, float* __restrict__ out) {
  __shared__ float s_lds[16][128];
  __shared__ __align__(16) unsigned short p_lds[16 * 128];
  __shared__ float m_st[16], l_st[16], osc_st[16];
  const int tid = threadIdx.x, lane = tid & 63, w = tid >> 6;
  const int lr = lane & 15, lg = lane >> 4, qb = blockIdx.x * 16;
  if (tid < 16) { m_st[tid] = -INFINITY; l_st[tid] = 0.f; }
  short8 qf[16];
  {
    const float* qp = q + (size_t)(qb + lr) * DIM + lg * 8;
#pragma unroll
    for (int c = 0; c < 16; ++c)
      qf[c] = pack8(*(const float4*)(qp + c * 32), *(const float4*)(qp + c * 32 + 4));
  }
  f32x4 oacc[4] = {};
  __syncthreads();
  for (int it = 0; it < SEQ / 128; ++it) {
    const int kb = it * 128;
    {
      const float* kp = k + (size_t)(kb + w * 16 + lr) * DIM + lg * 8;
      f32x4 sacc = {};
#pragma unroll
      for (int c = 0; c < 16; ++c) {
        short8 kf = pack8(*(const float4*)(kp + c * 32), *(const float4*)(kp + c * 32 + 4));
        sacc = __builtin_amdgcn_mfma_f32_16x16x32_bf16(qf[c], kf, sacc, 0, 0, 0);
      }
#pragma unroll
      for (int r = 0; r < 4; ++r) s_lds[lg * 4 + r][w * 16 + lr] = sacc[r] * SCALE;
    }
    __syncthreads();
    {
      const int srow = tid >> 5, sj = tid & 31;
      float4 sv = *(const float4*)&s_lds[srow][sj * 4];
      float tmax = fmaxf(fmaxf(sv.x, sv.y), fmaxf(sv.z, sv.w));
#pragma unroll
      for (int m = 16; m >= 1; m >>= 1) tmax = fmaxf(tmax, __shfl_xor(tmax, m));
      float mold = m_st[srow], mnew = fmaxf(mold, tmax);
      float p0 = __expf(sv.x - mnew), p1 = __expf(sv.y - mnew);
      float p2 = __expf(sv.z - mnew), p3 = __expf(sv.w - mnew);
      float psum = (p0 + p1) + (p2 + p3);
#pragma unroll
      for (int m = 16; m >= 1; m >>= 1) psum += __shfl_xor(psum, m);
      if (sj == 0) {
        float sc = __expf(mold - mnew);
        l_st[srow] = l_st[srow] * sc + psum; m_st[srow] = mnew; osc_st[srow] = sc;
      }
      ushort4 pb;
      pb.x = (unsigned short)f2bf(p0); pb.y = (unsigned short)f2bf(p1);
      pb.z = (unsigned short)f2bf(p2); pb.w = (unsigned short)f2bf(p3);
      int lin = srow * 256 + sj * 8;
      *(ushort4*)((char*)p_lds + (lin ^ ((srow & 7) << 4))) = pb;
    }
    __syncthreads();
    {
      float osc[4];
#pragma unroll
      for (int r = 0; r < 4; ++r) osc[r] = osc_st[lg * 4 + r];
#pragma unroll
      for (int ct = 0; ct < 4; ++ct)
#pragma unroll
        for (int r = 0; r < 4; ++r) oacc[ct][r] *= osc[r];
#pragma unroll
      for (int kc = 0; kc < 4; ++kc) {
        int lin = lr * 256 + (kc * 32 + 8 * lg) * 2;
        short8 pf = *(const short8*)((const char*)p_lds + (lin ^ ((lr & 7) << 4)));
        const float* vp0 = v + (size_t)(kb + kc * 32 + 8 * lg) * DIM + w * 64 + lr;
#pragma unroll
        for (int ct = 0; ct < 4; ++ct) {
          const float* vp = vp0 + ct * 16;
          short8 vf;
#pragma unroll
          for (int jj = 0; jj < 8; ++jj) vf[jj] = f2bf(vp[(size_t)jj * DIM]);
          oacc[ct] = __builtin_amdgcn_mfma_f32_16x16x32_bf16(pf, vf, oacc[ct], 0, 0, 0);
        }
      }
    }
    __syncthreads();
  }
  {
    float linv[4];
#pragma unroll
    for (int r = 0; r < 4; ++r) linv[r] = 1.f / l_st[lg * 4 + r];
#pragma unroll
    for (int ct = 0; ct < 4; ++ct)
#pragma unroll
      for (int r = 0; r < 4; ++r)
        out[(size_t)(qb + lg * 4 + r) * DIM + w * 64 + ct * 16 + lr] =
            oacc[ct][r] * linv[r];
  }
}

extern "C" void kernel_launch(void* const* d_in, const int* in_sizes, int n_in,
                              void* d_out, int out_size, void* d_ws, size_t ws_size,
                              hipStream_t stream) {
  (void)in_sizes; (void)n_in; (void)out_size;
  const float* q = (const float*)d_in[0];
  const float* k = (const float*)d_in[1];
  const float* v = (const float*)d_in[2];
  float* out = (float*)d_out;

  const size_t kbf_elems = (size_t)SEQ * DIM;
  const size_t qbf_elems = (size_t)SEQ * DIM;
  const size_t vt_elems  = (size_t)DIM * SEQ;
  const size_t op_elems  = (size_t)SPLITS * SEQ * DIM;   // bf16
  const size_t ml_elems  = (size_t)SPLITS * SEQ * 2;
  const size_t need = kbf_elems * 2 + qbf_elems * 2 + vt_elems * 2 +
                      op_elems * 2 + ml_elems * 4;

  if (ws_size >= need) {
    ushort* kbf   = (ushort*)d_ws;
    ushort* qbf   = kbf + kbf_elems;
    ushort* vtb   = qbf + qbf_elems;
    ushort* opart = vtb + vt_elems;
    float* ml     = (float*)(opart + op_elems);

    prep_fused<<<2048 + (SEQ / 64) * (DIM / 64), 256, 0, stream>>>(k, kbf, q, qbf, v, vtb);
    attn_split<<<(SEQ / BQ) * SPLITS, 512, 0, stream>>>(qbf, kbf, vtb, opart, ml);
    combine<<<(SEQ * DIM / 8) / 256, 256, 0, stream>>>(opart, ml, out);
  } else {
    attn_fused_fb<<<SEQ / 16, 512, 0, stream>>>(q, k, v, out);
  }
}